// Round 15
// baseline (234.403 us; speedup 1.0000x reference)
//
#include <hip/hip_runtime.h>
#include <hip/hip_bf16.h>

#define SCALE 0.07216878364870322f   // (3*64)^-0.5
#define LOG2E 1.4426950408889634f
// Q is pre-scaled by SCALE*LOG2E so attention logits are in log2 units.

typedef __bf16 bf16x8 __attribute__((ext_vector_type(8)));
typedef float f32x16 __attribute__((ext_vector_type(16)));
typedef float f32x4v __attribute__((ext_vector_type(4)));
typedef unsigned int u32x4 __attribute__((ext_vector_type(4)));
typedef unsigned int u32x2 __attribute__((ext_vector_type(2)));
typedef unsigned short u16;

#define MFMA(a, b, c) __builtin_amdgcn_mfma_f32_32x32x16_bf16(a, b, c, 0, 0, 0)
#define MFMA16(a, b, c) __builtin_amdgcn_mfma_f32_16x16x32_bf16(a, b, c, 0, 0, 0)

__device__ __forceinline__ u16 b16(float v) { return __builtin_bit_cast(u16, (__bf16)v); }
__device__ __forceinline__ float fb16(u16 u) {
    unsigned int t = (unsigned int)u << 16;
    return __builtin_bit_cast(float, t);
}
__device__ __forceinline__ unsigned int splitpack(float v) {
    u16 h = b16(v);
    float r = v - fb16(h);
    return (unsigned int)h | ((unsigned int)b16(r) << 16);
}
__device__ __forceinline__ unsigned int pack2(float a, float b) {
    return (unsigned int)b16(a) | ((unsigned int)b16(b) << 16);
}
__device__ __forceinline__ void gload16(const void* g, void* l) {
    __builtin_amdgcn_global_load_lds((const __attribute__((address_space(1))) void*)g,
                                     (__attribute__((address_space(3))) void*)l, 16, 0, 0);
}

// ---------------- K0: presplit x / w_qkv / w_out into bf16 hi+lo planes ------
// x: [b][n][i256][c3] f32 -> xhi/xlo [b][n][c3][i256] bf16 (c-deinterleaved)
// w_qkv: [1536][256] f32 -> whi/wlo same order
// w_out: [256][512] f32 -> wohi/wolo same order
__global__ __launch_bounds__(256) void presplit(const float* __restrict__ x,
                                                const float* __restrict__ wq,
                                                const float* __restrict__ wo,
                                                u16* __restrict__ xhi, u16* __restrict__ xlo,
                                                u16* __restrict__ whi, u16* __restrict__ wlo,
                                                u16* __restrict__ wohi, u16* __restrict__ wolo) {
    const int bid = blockIdx.x;
    const int t = threadIdx.x;
    if (bid < 4096) {                     // x rows
        const float* xr = x + (size_t)bid * 768 + t * 3;
        u16* oh = xhi + (size_t)bid * 768;
        u16* ol = xlo + (size_t)bid * 768;
        #pragma unroll
        for (int c = 0; c < 3; ++c) {
            float v = xr[c];
            u16 h = b16(v);
            oh[c * 256 + t] = h;
            ol[c * 256 + t] = b16(v - fb16(h));
        }
    } else if (bid < 4192) {              // w_qkv: 96 blocks x 4096 elems
        size_t base = (size_t)(bid - 4096) * 4096 + t * 16;
        #pragma unroll
        for (int q = 0; q < 4; ++q) {
            f32x4v v = *(const f32x4v*)(wq + base + q * 4);
            u16 h0 = b16(v[0]), h1 = b16(v[1]), h2 = b16(v[2]), h3 = b16(v[3]);
            *(u32x2*)(whi + base + q * 4) =
                u32x2{ (unsigned)h0 | ((unsigned)h1 << 16), (unsigned)h2 | ((unsigned)h3 << 16) };
            u16 l0 = b16(v[0] - fb16(h0)), l1 = b16(v[1] - fb16(h1));
            u16 l2 = b16(v[2] - fb16(h2)), l3 = b16(v[3] - fb16(h3));
            *(u32x2*)(wlo + base + q * 4) =
                u32x2{ (unsigned)l0 | ((unsigned)l1 << 16), (unsigned)l2 | ((unsigned)l3 << 16) };
        }
    } else {                              // w_out: 32 blocks x 4096 elems
        size_t base = (size_t)(bid - 4192) * 4096 + t * 16;
        #pragma unroll
        for (int q = 0; q < 4; ++q) {
            f32x4v v = *(const f32x4v*)(wo + base + q * 4);
            u16 h0 = b16(v[0]), h1 = b16(v[1]), h2 = b16(v[2]), h3 = b16(v[3]);
            *(u32x2*)(wohi + base + q * 4) =
                u32x2{ (unsigned)h0 | ((unsigned)h1 << 16), (unsigned)h2 | ((unsigned)h3 << 16) };
            u16 l0 = b16(v[0] - fb16(h0)), l1 = b16(v[1] - fb16(h1));
            u16 l2 = b16(v[2] - fb16(h2)), l3 = b16(v[3] - fb16(h3));
            *(u32x2*)(wolo + base + q * 4) =
                u32x2{ (unsigned)l0 | ((unsigned)l1 << 16), (unsigned)l2 | ((unsigned)l3 << 16) };
        }
    }
}

// ---------------- K1: QKV projection, pre-split operands, pure load+MFMA -----
// Flat grid 768, XCD-remapped: all 24 o-blocks sharing one (n,b) x-slice land
// on one XCD (x slice L2-resident).
__global__ __launch_bounds__(256) void qkv_mfma(const u16* __restrict__ xhi,
                                                const u16* __restrict__ xlo,
                                                const u16* __restrict__ whi,
                                                const u16* __restrict__ wlo,
                                                u16* __restrict__ Qhi, u16* __restrict__ Qlo,
                                                u16* __restrict__ KVf) {
    __shared__ unsigned int ldsr[2][32][196];
    const int tid = threadIdx.x;
    const int lane = tid & 63, w = tid >> 6, hf = lane >> 5, l31 = lane & 31;
    const int lq = lane & 15, gq = lane >> 4;   // 16x16-frag coords
    const int id = blockIdx.x;           // 0..767
    const int xcd = id & 7;
    const int jj = id >> 3;              // 0..95
    const int nb = xcd * 4 + jj / 24;    // 0..31
    const int ot = jj % 24;              // 0..23
    const int o0 = ot * 64;
    const int b = nb >> 4;
    const int n0 = (nb & 15) * 128;
    const int nw0 = n0 + w * 32;
    const int part = o0 >> 9;
    const int h = (o0 >> 6) & 7;
    const int bh = b * 8 + h;

    const size_t xbase = (size_t)(b * 2048 + nw0 + l31) * 768 + hf * 8;
    const size_t wbase0 = (size_t)(o0 + l31) * 256 + hf * 8;
    const size_t wbase1 = wbase0 + 32 * 256;

    f32x16 acc[3][2] = {};
    #pragma unroll 2
    for (int k0 = 0; k0 < 16; ++k0) {
        bf16x8 xh[3], xl[3], wh[2], wl[2];
        #pragma unroll
        for (int c = 0; c < 3; ++c) {
            xh[c] = *(const bf16x8*)(xhi + xbase + c * 256 + k0 * 16);
            xl[c] = *(const bf16x8*)(xlo + xbase + c * 256 + k0 * 16);
        }
        wh[0] = *(const bf16x8*)(whi + wbase0 + k0 * 16);
        wl[0] = *(const bf16x8*)(wlo + wbase0 + k0 * 16);
        wh[1] = *(const bf16x8*)(whi + wbase1 + k0 * 16);
        wl[1] = *(const bf16x8*)(wlo + wbase1 + k0 * 16);
        #pragma unroll
        for (int c = 0; c < 3; ++c)
            #pragma unroll
            for (int ot2 = 0; ot2 < 2; ++ot2) {
                acc[c][ot2] = MFMA(xh[c], wh[ot2], acc[c][ot2]);
                acc[c][ot2] = MFMA(xl[c], wh[ot2], acc[c][ot2]);
                acc[c][ot2] = MFMA(xh[c], wl[ot2], acc[c][ot2]);
            }
    }

    #pragma unroll
    for (int round = 0; round < 2; ++round) {
        __syncthreads();
        if ((w >> 1) == round) {
            unsigned int (*L)[196] = ldsr[w & 1];
            #pragma unroll
            for (int c = 0; c < 3; ++c)
                #pragma unroll
                for (int ot2 = 0; ot2 < 2; ++ot2)
                    #pragma unroll
                    for (int r = 0; r < 16; ++r) {
                        float v = acc[c][ot2][r];
                        if (part == 0) v *= (SCALE * LOG2E);
                        int nn = (r & 3) + 8 * (r >> 2) + 4 * hf;
                        int dcol = 3 * (ot2 * 32 + l31) + c;
                        L[nn][dcol] = (part == 2) ? (unsigned int)b16(v) : splitpack(v);
                    }
            if (part < 2) {
                #pragma unroll
                for (int is = 0; is < 2; ++is)
                    #pragma unroll
                    for (int kc = 0; kc < 6; ++kc) {
                        const unsigned int* p = &L[is * 16 + lq][kc * 32 + gq * 8];
                        u32x4 a = *(const u32x4*)p;
                        u32x4 bq = *(const u32x4*)(p + 4);
                        u32x4 hi = { (a[0] & 0xffffu) | (a[1] << 16), (a[2] & 0xffffu) | (a[3] << 16),
                                     (bq[0] & 0xffffu) | (bq[1] << 16), (bq[2] & 0xffffu) | (bq[3] << 16) };
                        u32x4 lo = { (a[0] >> 16) | (a[1] & 0xffff0000u), (a[2] >> 16) | (a[3] & 0xffff0000u),
                                     (bq[0] >> 16) | (bq[1] & 0xffff0000u), (bq[2] >> 16) | (bq[3] & 0xffff0000u) };
                        if (part == 0) {
                            size_t off = ((size_t)(bh * 128 + (nw0 >> 4) + is) * 6 + kc) * 512 + lane * 8;
                            *(u32x4*)(Qhi + off) = hi;
                            *(u32x4*)(Qlo + off) = lo;
                        } else {
                            size_t off = (size_t)(bh * 64 + (nw0 >> 5)) * 18432 + (is * 6 + kc) * 512 + lane * 8;
                            *(u32x4*)(KVf + off) = hi;
                            *(u32x4*)(KVf + off + 6144) = lo;
                        }
                    }
            } else {
                u16* vp = KVf + (size_t)(bh * 64 + (nw0 >> 5)) * 18432 + 12288 + lane * 8;
                #pragma unroll
                for (int d = 0; d < 12; ++d) {
                    unsigned int t[8];
                    #pragma unroll
                    for (int e = 0; e < 8; ++e)
                        t[e] = L[gq * 8 + e][d * 16 + lq];
                    u32x4 pk = { (t[0] & 0xffffu) | (t[1] << 16), (t[2] & 0xffffu) | (t[3] << 16),
                                 (t[4] & 0xffffu) | (t[5] << 16), (t[6] & 0xffffu) | (t[7] << 16) };
                    *(u32x4*)(vp + d * 512) = pk;
                }
            }
        }
    }
}

// ---------------- K2: MFMA flash attention (R11 loop), 32 i-rows/wave --------
// grid 512 (XCD-swizzled), block 256, launch_bounds(256,2) -> 2 waves/SIMD,
// 72KB dbuf -> 2 blocks/CU. Epilogue: LDS transpose -> coalesced u32x4 stores.
__global__ __launch_bounds__(256, 2) void attn_mfma(
    const u16* __restrict__ Qhi, const u16* __restrict__ Qlo,
    const u16* __restrict__ KVf, u16* __restrict__ OpA, u16* __restrict__ OpB,
    float2* __restrict__ MLp) {
    __shared__ __align__(16) u16 lds[2][18432];  // per buf: Khi[6144]|Klo[6144]|V[6144]
    const int tid = threadIdx.x;
    const int lane = tid & 63;
    const int wl = tid >> 6;         // 0..3
    const int g = lane >> 4;         // 0..3
    const int i = lane & 15;
    const int id = blockIdx.x;                     // 0..511
    const int rem = id >> 3;                       // 0..63
    const int grp = ((rem >> 4) << 3) | (id & 7);  // 0..31: (bh,half)
    const int itile = rem & 15;                    // 0..15
    const int bh = grp >> 1;
    const int half = grp & 1;

    bf16x8 qh[2][6], ql[2][6];
    #pragma unroll
    for (int is = 0; is < 2; ++is) {
        size_t qb = (size_t)(bh * 128 + itile * 8 + wl * 2 + is) * 3072 + (size_t)lane * 8;
        #pragma unroll
        for (int kc = 0; kc < 6; ++kc) {
            qh[is][kc] = *(const bf16x8*)(Qhi + qb + kc * 512);
            ql[is][kc] = *(const bf16x8*)(Qlo + qb + kc * 512);
        }
    }

    const char* gKV = (const char*)KVf + (size_t)bh * 2359296;  // 64 tiles * 36864 B
    auto stage = [&](int buf, int jtAbs) {
        const char* src = gKV + (size_t)jtAbs * 36864;
        char* dst = (char*)&lds[buf][0];
        #pragma unroll
        for (int s = 0; s < 9; ++s) {
            const int c16 = (tid + s * 256) * 16;
            gload16(src + c16, dst + c16);
        }
    };

    const int jt0 = half * 32;
    stage(0, jt0);
    __syncthreads();
    int cur = 0;

    f32x4v o[2][12] = {};
    float m_run[2] = {-1e30f, -1e30f}, l_run[2] = {0.f, 0.f};

    for (int t = 0; t < 32; ++t) {
        if (t + 1 < 32) stage(cur ^ 1, jt0 + t + 1);
        const u16* L = &lds[cur][0];

        f32x4v s4[2][2] = {};   // [iset][js]
        __builtin_amdgcn_s_setprio(1);
        #pragma unroll
        for (int kc = 0; kc < 6; ++kc) {
            bf16x8 kh0 = *(const bf16x8*)&L[(unsigned)(kc * 512) + lane * 8];
            bf16x8 kh1 = *(const bf16x8*)&L[(unsigned)((6 + kc) * 512) + lane * 8];
            bf16x8 kl0 = *(const bf16x8*)&L[6144u + (unsigned)(kc * 512) + lane * 8];
            bf16x8 kl1 = *(const bf16x8*)&L[6144u + (unsigned)((6 + kc) * 512) + lane * 8];
            s4[0][0] = MFMA16(kh0, qh[0][kc], s4[0][0]);
            s4[0][1] = MFMA16(kh1, qh[0][kc], s4[0][1]);
            s4[1][0] = MFMA16(kh0, qh[1][kc], s4[1][0]);
            s4[1][1] = MFMA16(kh1, qh[1][kc], s4[1][1]);
            s4[0][0] = MFMA16(kh0, ql[0][kc], s4[0][0]);
            s4[0][1] = MFMA16(kh1, ql[0][kc], s4[0][1]);
            s4[1][0] = MFMA16(kh0, ql[1][kc], s4[1][0]);
            s4[1][1] = MFMA16(kh1, ql[1][kc], s4[1][1]);
            s4[0][0] = MFMA16(kl0, qh[0][kc], s4[0][0]);
            s4[0][1] = MFMA16(kl1, qh[0][kc], s4[0][1]);
            s4[1][0] = MFMA16(kl0, qh[1][kc], s4[1][0]);
            s4[1][1] = MFMA16(kl1, qh[1][kc], s4[1][1]);
        }
        __builtin_amdgcn_s_setprio(0);

        bf16x8 pb[2];
        #pragma unroll
        for (int is = 0; is < 2; ++is) {
            float pm = -1e30f;
            #pragma unroll
            for (int js = 0; js < 2; ++js)
                #pragma unroll
                for (int r = 0; r < 4; ++r) pm = fmaxf(pm, s4[is][js][r]);
            pm = fmaxf(pm, __shfl_xor(pm, 16, 64));
            pm = fmaxf(pm, __shfl_xor(pm, 32, 64));
            if (!__all(pm <= m_run[is] + 8.0f)) {   // T13 defer-rescale
                float mnew = fmaxf(m_run[is], pm);
                float sc = exp2f(m_run[is] - mnew);
                l_run[is] *= sc;
                #pragma unroll
                for (int d = 0; d < 12; ++d) o[is][d] = o[is][d] * sc;
                m_run[is] = mnew;
            }
            float rs = 0.f;
            unsigned int w0[2], w1[2];
            #pragma unroll
            for (int js = 0; js < 2; ++js) {
                float p0 = exp2f(s4[is][js][0] - m_run[is]), p1 = exp2f(s4[is][js][1] - m_run[is]);
                float p2 = exp2f(s4[is][js][2] - m_run[is]), p3 = exp2f(s4[is][js][3] - m_run[is]);
                rs += (p0 + p1) + (p2 + p3);
                w0[js] = pack2(p0, p1);
                w1[js] = pack2(p2, p3);
            }
            rs += __shfl_xor(rs, 16, 64);
            rs += __shfl_xor(rs, 32, 64);
            l_run[is] += rs;

            u32x4 F;
            const int slA = ((g & 1) << 5) + i;
            const int slB = slA + 16;
            const bool ghi = (g >> 1) != 0;
            { unsigned a0 = __shfl((int)w0[0], slA, 64), a1 = __shfl((int)w0[1], slA, 64); F[0] = ghi ? a1 : a0; }
            { unsigned a0 = __shfl((int)w1[0], slA, 64), a1 = __shfl((int)w1[1], slA, 64); F[1] = ghi ? a1 : a0; }
            { unsigned a0 = __shfl((int)w0[0], slB, 64), a1 = __shfl((int)w0[1], slB, 64); F[2] = ghi ? a1 : a0; }
            { unsigned a0 = __shfl((int)w1[0], slB, 64), a1 = __shfl((int)w1[1], slB, 64); F[3] = ghi ? a1 : a0; }
            pb[is] = __builtin_bit_cast(bf16x8, F);
        }

        __builtin_amdgcn_s_setprio(1);
        #pragma unroll
        for (int d = 0; d < 12; ++d) {
            bf16x8 vf = *(const bf16x8*)&L[12288u + (unsigned)(d * 512) + lane * 8];
            o[0][d] = MFMA16(vf, pb[0], o[0][d]);
            o[1][d] = MFMA16(vf, pb[1], o[1][d]);
        }
        __builtin_amdgcn_s_setprio(0);

        if (t + 1 < 32) {
            __syncthreads();
            cur ^= 1;
        }
    }

    // ---- epilogue: LDS transpose (row-stride 196 u16) -> coalesced stores ----
    __syncthreads();
    u16* LS = &lds[0][0];
    #pragma unroll
    for (int is = 0; is < 2; ++is) {
        const int row = (wl * 2 + is) * 16 + i;
        #pragma unroll
        for (int d = 0; d < 12; ++d) {
            u32x2 pk = { pack2(o[is][d][0], o[is][d][1]), pack2(o[is][d][2], o[is][d][3]) };
            *(u32x2*)&LS[row * 196 + d * 16 + g * 4] = pk;
        }
        if (g == 0) {
            const int ig = itile * 128 + row;
            float2 ml; ml.x = m_run[is]; ml.y = l_run[is];
            MLp[(size_t)half * 32768 + bh * 2048 + ig] = ml;
        }
    }
    __syncthreads();
    const int b2 = bh >> 3, hh = bh & 7;
    u16* P = half ? OpB : OpA;
    #pragma unroll
    for (int v = 0; v < 12; ++v) {
        const int Lx = v * 256 + tid;        // 0..3071
        const int ln   = Lx & 63;
        const int itql = (Lx >> 6) & 3;
        const int ksl  = (Lx >> 8) & 3;
        const int c    = Lx >> 10;           // 0..2
        const int i31 = ln & 31, b5 = ln >> 5;
        const int rowl = itql * 32 + i31;
        unsigned tv[8];
        #pragma unroll
        for (int e = 0; e < 8; ++e) {
            const int dd = ksl * 16 + b5 * 8 + e;
            tv[e] = LS[rowl * 196 + dd * 3 + c];
        }
        u32x4 pk = { tv[0] | (tv[1] << 16), tv[2] | (tv[3] << 16),
                     tv[4] | (tv[5] << 16), tv[6] | (tv[7] << 16) };
        size_t off = (((size_t)(b2 * 3 + c) * 32 + (hh * 4 + ksl)) * 64 + (itile * 4 + itql)) * 512
                     + (size_t)ln * 8;
        *(u32x4*)(P + off) = pk;
    }
}

// ---------------- K3: output projection + inline flash merge -----------------
__global__ __launch_bounds__(256) void out_mfma(const u16* __restrict__ OpA,
                                                const u16* __restrict__ OpB,
                                                const float2* __restrict__ MLp,
                                                const u16* __restrict__ wohi,
                                                const u16* __restrict__ wolo,
                                                float* __restrict__ out) {
    const int tid = threadIdx.x, lane = tid & 63, w = tid >> 6, hf = lane >> 5, l31 = lane & 31;
    const int o0 = blockIdx.x * 32;
    const int n5 = blockIdx.y * 4 + w;
    const int b = blockIdx.z;
    const size_t wbase = (size_t)(o0 + l31) * 512 + hf * 8;

    float wa[8], wb[8], inv[8];
    #pragma unroll
    for (int hh = 0; hh < 8; ++hh) {
        size_t mi = (size_t)(b * 8 + hh) * 2048 + n5 * 32 + l31;
        float2 A = MLp[mi];
        float2 Bm = MLp[32768 + mi];
        float mm = fmaxf(A.x, Bm.x);
        wa[hh] = exp2f(A.x - mm);
        wb[hh] = exp2f(Bm.x - mm);
        inv[hh] = 1.0f / (A.y * wa[hh] + Bm.y * wb[hh]);
    }

    f32x16 acc[3] = {};
    #pragma unroll 2
    for (int ks = 0; ks < 32; ++ks) {
        const int hh = ks >> 2;
        const float waH = wa[hh], wbH = wb[hh], invH = inv[hh];
        bf16x8 wh = *(const bf16x8*)(wohi + wbase + ks * 16);
        bf16x8 wl = *(const bf16x8*)(wolo + wbase + ks * 16);
        #pragma unroll
        for (int c = 0; c < 3; ++c) {
            size_t pc = (size_t)(b * 3 + c) * 1048576 + (size_t)ks * 32768 + (size_t)n5 * 512 + (size_t)lane * 8;
            u32x4 aA = *(const u32x4*)(OpA + pc);
            u32x4 aB = *(const u32x4*)(OpB + pc);
            unsigned hiw[4], low[4];
            #pragma unroll
            for (int q = 0; q < 4; ++q) {
                unsigned ha = 0, la = 0;
                #pragma unroll
                for (int s = 0; s < 2; ++s) {
                    u16 ua = (u16)((aA[q] >> (s * 16)) & 0xffffu);
                    u16 ub = (u16)((aB[q] >> (s * 16)) & 0xffffu);
                    float v = (fb16(ua) * waH + fb16(ub) * wbH) * invH;
                    u16 hv = b16(v);
                    u16 lv = b16(v - fb16(hv));
                    ha |= ((unsigned)hv) << (s * 16);
                    la |= ((unsigned)lv) << (s * 16);
                }
                hiw[q] = ha; low[q] = la;
            }
            union { bf16x8 v; u32x4 u; } H, Lo;
            H.u  = { hiw[0], hiw[1], hiw[2], hiw[3] };
            Lo.u = { low[0], low[1], low[2], low[3] };
            acc[c] = MFMA(H.v, wh, acc[c]);
            acc[c] = MFMA(Lo.v, wh, acc[c]);
            acc[c] = MFMA(H.v, wl, acc[c]);
        }
    }
    #pragma unroll
    for (int r = 0; r < 16; ++r) {
        int n = (n5 << 5) + (r & 3) + 8 * (r >> 2) + 4 * hf;
        size_t off = ((size_t)(b * 2048 + n) * 256 + o0 + l31) * 3;
        out[off]     = acc[0][r];
        out[off + 1] = acc[1][r];
        out[off + 2] = acc[2][r];
    }
}

extern "C" void kernel_launch(void* const* d_in, const int* in_sizes, int n_in,
                              void* d_out, int out_size, void* d_ws, size_t ws_size,
                              hipStream_t stream) {
    const float* x     = (const float*)d_in[0];
    const float* w_qkv = (const float*)d_in[1];
    const float* w_out = (const float*)d_in[2];
    float* out = (float*)d_out;

    const size_t NB = (size_t)16 * 2048 * 192;       // 6.29M u16 per plane
    const size_t KVN = (size_t)16 * 64 * 18432;      // 18.87M u16 (37.7MB)
    u16* Qhi = (u16*)d_ws;
    u16* Qlo = Qhi + NB;
    u16* KVf = Qlo + NB;
    u16* OpA = KVf + KVN;                            // 12.6MB
    u16* OpB = OpA + NB;                             // 12.6MB
    float2* MLp = (float2*)(OpB + NB);               // 512KB
    u16* xhi = (u16*)(MLp + 65536);                  // 6.3MB
    u16* xlo = xhi + (size_t)4096 * 768;
    u16* whi = xlo + (size_t)4096 * 768;             // 0.79MB
    u16* wlo = whi + (size_t)1536 * 256;
    u16* wohi = wlo + (size_t)1536 * 256;            // 0.26MB
    u16* wolo = wohi + (size_t)256 * 512;

    presplit<<<dim3(4224), 256, 0, stream>>>(x, w_qkv, w_out, xhi, xlo, whi, wlo, wohi, wolo);
    qkv_mfma<<<dim3(768), 256, 0, stream>>>(xhi, xlo, whi, wlo, Qhi, Qlo, KVf);
    attn_mfma<<<dim3(512), 256, 0, stream>>>(Qhi, Qlo, KVf, OpA, OpB, MLp);
    out_mfma<<<dim3(8, 16, 2), 256, 0, stream>>>(OpA, OpB, MLp, wohi, wolo, out);
}

// Round 16
// 221.044 us; speedup vs baseline: 1.0604x; 1.0604x over previous
//
#include <hip/hip_runtime.h>
#include <hip/hip_bf16.h>

#define SCALE 0.07216878364870322f   // (3*64)^-0.5
#define LOG2E 1.4426950408889634f
// Q is pre-scaled by SCALE*LOG2E so attention logits are in log2 units.

typedef __bf16 bf16x8 __attribute__((ext_vector_type(8)));
typedef float f32x16 __attribute__((ext_vector_type(16)));
typedef float f32x4v __attribute__((ext_vector_type(4)));
typedef unsigned int u32x4 __attribute__((ext_vector_type(4)));
typedef unsigned int u32x2 __attribute__((ext_vector_type(2)));
typedef unsigned short u16;

#define MFMA(a, b, c) __builtin_amdgcn_mfma_f32_32x32x16_bf16(a, b, c, 0, 0, 0)
#define MFMA16(a, b, c) __builtin_amdgcn_mfma_f32_16x16x32_bf16(a, b, c, 0, 0, 0)

__device__ __forceinline__ u16 b16(float v) { return __builtin_bit_cast(u16, (__bf16)v); }
__device__ __forceinline__ float fb16(u16 u) {
    unsigned int t = (unsigned int)u << 16;
    return __builtin_bit_cast(float, t);
}
__device__ __forceinline__ unsigned int splitpack(float v) {
    u16 h = b16(v);
    float r = v - fb16(h);
    return (unsigned int)h | ((unsigned int)b16(r) << 16);
}
__device__ __forceinline__ unsigned int pack2(float a, float b) {
    return (unsigned int)b16(a) | ((unsigned int)b16(b) << 16);
}
__device__ __forceinline__ void gload16(const void* g, void* l) {
    __builtin_amdgcn_global_load_lds((const __attribute__((address_space(1))) void*)g,
                                     (__attribute__((address_space(3))) void*)l, 16, 0, 0);
}

// ---------------- K0: presplit WEIGHTS ONLY into bf16 hi+lo planes -----------
// w_qkv: [1536][256] f32 -> whi/wlo   (blocks 0..95)
// w_out: [256][512]  f32 -> wohi/wolo (blocks 96..127)
__global__ __launch_bounds__(256) void presplitW(const float* __restrict__ wq,
                                                 const float* __restrict__ wo,
                                                 u16* __restrict__ whi, u16* __restrict__ wlo,
                                                 u16* __restrict__ wohi, u16* __restrict__ wolo) {
    const int bid = blockIdx.x;
    const int t = threadIdx.x;
    const float* src = (bid < 96) ? wq : wo;
    u16* dh = (bid < 96) ? whi : wohi;
    u16* dl = (bid < 96) ? wlo : wolo;
    size_t base = (size_t)(bid < 96 ? bid : bid - 96) * 4096 + t * 16;
    #pragma unroll
    for (int q = 0; q < 4; ++q) {
        f32x4v v = *(const f32x4v*)(src + base + q * 4);
        u16 h0 = b16(v[0]), h1 = b16(v[1]), h2 = b16(v[2]), h3 = b16(v[3]);
        *(u32x2*)(dh + base + q * 4) =
            u32x2{ (unsigned)h0 | ((unsigned)h1 << 16), (unsigned)h2 | ((unsigned)h3 << 16) };
        u16 l0 = b16(v[0] - fb16(h0)), l1 = b16(v[1] - fb16(h1));
        u16 l2 = b16(v[2] - fb16(h2)), l3 = b16(v[3] - fb16(h3));
        *(u32x2*)(dl + base + q * 4) =
            u32x2{ (unsigned)l0 | ((unsigned)l1 << 16), (unsigned)l2 | ((unsigned)l3 << 16) };
    }
}

// ---------------- K1: QKV projection, split-bf16 (x in-loop, W presplit) -----
// Flat grid 768, XCD-remapped: all 24 o-blocks sharing one (n,b) x-slice land
// on one XCD (x slice L2-resident). x reads stay contiguous f32 (96B/lane).
__global__ __launch_bounds__(256) void qkv_mfma(const float* __restrict__ x,
                                                const u16* __restrict__ whi,
                                                const u16* __restrict__ wlo,
                                                u16* __restrict__ Qhi, u16* __restrict__ Qlo,
                                                u16* __restrict__ KVf) {
    __shared__ unsigned int ldsr[2][32][196];
    const int tid = threadIdx.x;
    const int lane = tid & 63, w = tid >> 6, hf = lane >> 5, l31 = lane & 31;
    const int lq = lane & 15, gq = lane >> 4;   // 16x16-frag coords
    const int id = blockIdx.x;           // 0..767
    const int xcd = id & 7;
    const int jj = id >> 3;              // 0..95
    const int nb = xcd * 4 + jj / 24;    // 0..31
    const int ot = jj % 24;              // 0..23
    const int o0 = ot * 64;
    const int b = nb >> 4;
    const int n0 = (nb & 15) * 128;
    const int nw0 = n0 + w * 32;
    const int part = o0 >> 9;
    const int h = (o0 >> 6) & 7;
    const int bh = b * 8 + h;

    const float* xp = x + ((size_t)(b * 2048 + nw0 + l31)) * 768 + hf * 24;
    const size_t wbase0 = (size_t)(o0 + l31) * 256 + hf * 8;
    const size_t wbase1 = wbase0 + 32 * 256;

    f32x16 acc[3][2] = {};
    #pragma unroll 2
    for (int k0 = 0; k0 < 16; ++k0) {
        float xf[24];
        #pragma unroll
        for (int q = 0; q < 6; ++q) {
            f32x4v t = *(const f32x4v*)(xp + k0 * 48 + q * 4);
            xf[q * 4 + 0] = t[0]; xf[q * 4 + 1] = t[1];
            xf[q * 4 + 2] = t[2]; xf[q * 4 + 3] = t[3];
        }
        bf16x8 xh[3], xl[3], wh[2], wl[2];
        #pragma unroll
        for (int c = 0; c < 3; ++c)
            #pragma unroll
            for (int e = 0; e < 8; ++e) {
                float v = xf[e * 3 + c];
                __bf16 hi = (__bf16)v;
                xh[c][e] = hi;
                xl[c][e] = (__bf16)(v - (float)hi);
            }
        wh[0] = *(const bf16x8*)(whi + wbase0 + k0 * 16);
        wl[0] = *(const bf16x8*)(wlo + wbase0 + k0 * 16);
        wh[1] = *(const bf16x8*)(whi + wbase1 + k0 * 16);
        wl[1] = *(const bf16x8*)(wlo + wbase1 + k0 * 16);
        #pragma unroll
        for (int c = 0; c < 3; ++c)
            #pragma unroll
            for (int ot2 = 0; ot2 < 2; ++ot2) {
                acc[c][ot2] = MFMA(xh[c], wh[ot2], acc[c][ot2]);
                acc[c][ot2] = MFMA(xl[c], wh[ot2], acc[c][ot2]);
                acc[c][ot2] = MFMA(xh[c], wl[ot2], acc[c][ot2]);
            }
    }

    #pragma unroll
    for (int round = 0; round < 2; ++round) {
        __syncthreads();
        if ((w >> 1) == round) {
            unsigned int (*L)[196] = ldsr[w & 1];
            #pragma unroll
            for (int c = 0; c < 3; ++c)
                #pragma unroll
                for (int ot2 = 0; ot2 < 2; ++ot2)
                    #pragma unroll
                    for (int r = 0; r < 16; ++r) {
                        float v = acc[c][ot2][r];
                        if (part == 0) v *= (SCALE * LOG2E);
                        int nn = (r & 3) + 8 * (r >> 2) + 4 * hf;
                        int dcol = 3 * (ot2 * 32 + l31) + c;
                        L[nn][dcol] = (part == 2) ? (unsigned int)b16(v) : splitpack(v);
                    }
            if (part < 2) {
                #pragma unroll
                for (int is = 0; is < 2; ++is)
                    #pragma unroll
                    for (int kc = 0; kc < 6; ++kc) {
                        const unsigned int* p = &L[is * 16 + lq][kc * 32 + gq * 8];
                        u32x4 a = *(const u32x4*)p;
                        u32x4 bq = *(const u32x4*)(p + 4);
                        u32x4 hi = { (a[0] & 0xffffu) | (a[1] << 16), (a[2] & 0xffffu) | (a[3] << 16),
                                     (bq[0] & 0xffffu) | (bq[1] << 16), (bq[2] & 0xffffu) | (bq[3] << 16) };
                        u32x4 lo = { (a[0] >> 16) | (a[1] & 0xffff0000u), (a[2] >> 16) | (a[3] & 0xffff0000u),
                                     (bq[0] >> 16) | (bq[1] & 0xffff0000u), (bq[2] >> 16) | (bq[3] & 0xffff0000u) };
                        if (part == 0) {
                            size_t off = ((size_t)(bh * 128 + (nw0 >> 4) + is) * 6 + kc) * 512 + lane * 8;
                            *(u32x4*)(Qhi + off) = hi;
                            *(u32x4*)(Qlo + off) = lo;
                        } else {
                            size_t off = (size_t)(bh * 64 + (nw0 >> 5)) * 18432 + (is * 6 + kc) * 512 + lane * 8;
                            *(u32x4*)(KVf + off) = hi;
                            *(u32x4*)(KVf + off + 6144) = lo;
                        }
                    }
            } else {
                u16* vp = KVf + (size_t)(bh * 64 + (nw0 >> 5)) * 18432 + 12288 + lane * 8;
                #pragma unroll
                for (int d = 0; d < 12; ++d) {
                    unsigned int t[8];
                    #pragma unroll
                    for (int e = 0; e < 8; ++e)
                        t[e] = L[gq * 8 + e][d * 16 + lq];
                    u32x4 pk = { (t[0] & 0xffffu) | (t[1] << 16), (t[2] & 0xffffu) | (t[3] << 16),
                                 (t[4] & 0xffffu) | (t[5] << 16), (t[6] & 0xffffu) | (t[7] << 16) };
                    *(u32x4*)(vp + d * 512) = pk;
                }
            }
        }
    }
}

// ---------------- K2: MFMA flash attention (R14 verbatim) --------------------
__global__ __launch_bounds__(256, 2) void attn_mfma(
    const u16* __restrict__ Qhi, const u16* __restrict__ Qlo,
    const u16* __restrict__ KVf, u16* __restrict__ OpA, u16* __restrict__ OpB,
    float2* __restrict__ MLp) {
    __shared__ __align__(16) u16 lds[2][18432];  // per buf: Khi[6144]|Klo[6144]|V[6144]
    const int tid = threadIdx.x;
    const int lane = tid & 63;
    const int wl = tid >> 6;         // 0..3
    const int g = lane >> 4;         // 0..3
    const int i = lane & 15;
    const int id = blockIdx.x;                     // 0..511
    const int rem = id >> 3;                       // 0..63
    const int grp = ((rem >> 4) << 3) | (id & 7);  // 0..31: (bh,half)
    const int itile = rem & 15;                    // 0..15
    const int bh = grp >> 1;
    const int half = grp & 1;

    bf16x8 qh[2][6], ql[2][6];
    #pragma unroll
    for (int is = 0; is < 2; ++is) {
        size_t qb = (size_t)(bh * 128 + itile * 8 + wl * 2 + is) * 3072 + (size_t)lane * 8;
        #pragma unroll
        for (int kc = 0; kc < 6; ++kc) {
            qh[is][kc] = *(const bf16x8*)(Qhi + qb + kc * 512);
            ql[is][kc] = *(const bf16x8*)(Qlo + qb + kc * 512);
        }
    }

    const char* gKV = (const char*)KVf + (size_t)bh * 2359296;  // 64 tiles * 36864 B
    auto stage = [&](int buf, int jtAbs) {
        const char* src = gKV + (size_t)jtAbs * 36864;
        char* dst = (char*)&lds[buf][0];
        #pragma unroll
        for (int s = 0; s < 9; ++s) {
            const int c16 = (tid + s * 256) * 16;
            gload16(src + c16, dst + c16);
        }
    };

    const int jt0 = half * 32;
    stage(0, jt0);
    __syncthreads();
    int cur = 0;

    f32x4v o[2][12] = {};
    float m_run[2] = {-1e30f, -1e30f}, l_run[2] = {0.f, 0.f};

    for (int t = 0; t < 32; ++t) {
        if (t + 1 < 32) stage(cur ^ 1, jt0 + t + 1);
        const u16* L = &lds[cur][0];

        f32x4v s4[2][2] = {};   // [iset][js]
        __builtin_amdgcn_s_setprio(1);
        #pragma unroll
        for (int kc = 0; kc < 6; ++kc) {
            bf16x8 kh0 = *(const bf16x8*)&L[(unsigned)(kc * 512) + lane * 8];
            bf16x8 kh1 = *(const bf16x8*)&L[(unsigned)((6 + kc) * 512) + lane * 8];
            bf16x8 kl0 = *(const bf16x8*)&L[6144u + (unsigned)(kc * 512) + lane * 8];
            bf16x8 kl1 = *(const bf16x8*)&L[6144u + (unsigned)((6 + kc) * 512) + lane * 8];
            s4[0][0] = MFMA16(kh0, qh[0][kc], s4[0][0]);
            s4[0][1] = MFMA16(kh1, qh[0][kc], s4[0][1]);
            s4[1][0] = MFMA16(kh0, qh[1][kc], s4[1][0]);
            s4[1][1] = MFMA16(kh1, qh[1][kc], s4[1][1]);
            s4[0][0] = MFMA16(kh0, ql[0][kc], s4[0][0]);
            s4[0][1] = MFMA16(kh1, ql[0][kc], s4[0][1]);
            s4[1][0] = MFMA16(kh0, ql[1][kc], s4[1][0]);
            s4[1][1] = MFMA16(kh1, ql[1][kc], s4[1][1]);
            s4[0][0] = MFMA16(kl0, qh[0][kc], s4[0][0]);
            s4[0][1] = MFMA16(kl1, qh[0][kc], s4[0][1]);
            s4[1][0] = MFMA16(kl0, qh[1][kc], s4[1][0]);
            s4[1][1] = MFMA16(kl1, qh[1][kc], s4[1][1]);
        }
        __builtin_amdgcn_s_setprio(0);

        bf16x8 pb[2];
        #pragma unroll
        for (int is = 0; is < 2; ++is) {
            float pm = -1e30f;
            #pragma unroll
            for (int js = 0; js < 2; ++js)
                #pragma unroll
                for (int r = 0; r < 4; ++r) pm = fmaxf(pm, s4[is][js][r]);
            pm = fmaxf(pm, __shfl_xor(pm, 16, 64));
            pm = fmaxf(pm, __shfl_xor(pm, 32, 64));
            if (!__all(pm <= m_run[is] + 8.0f)) {   // T13 defer-rescale
                float mnew = fmaxf(m_run[is], pm);
                float sc = exp2f(m_run[is] - mnew);
                l_run[is] *= sc;
                #pragma unroll
                for (int d = 0; d < 12; ++d) o[is][d] = o[is][d] * sc;
                m_run[is] = mnew;
            }
            float rs = 0.f;
            unsigned int w0[2], w1[2];
            #pragma unroll
            for (int js = 0; js < 2; ++js) {
                float p0 = exp2f(s4[is][js][0] - m_run[is]), p1 = exp2f(s4[is][js][1] - m_run[is]);
                float p2 = exp2f(s4[is][js][2] - m_run[is]), p3 = exp2f(s4[is][js][3] - m_run[is]);
                rs += (p0 + p1) + (p2 + p3);
                w0[js] = pack2(p0, p1);
                w1[js] = pack2(p2, p3);
            }
            rs += __shfl_xor(rs, 16, 64);
            rs += __shfl_xor(rs, 32, 64);
            l_run[is] += rs;

            u32x4 F;
            const int slA = ((g & 1) << 5) + i;
            const int slB = slA + 16;
            const bool ghi = (g >> 1) != 0;
            { unsigned a0 = __shfl((int)w0[0], slA, 64), a1 = __shfl((int)w0[1], slA, 64); F[0] = ghi ? a1 : a0; }
            { unsigned a0 = __shfl((int)w1[0], slA, 64), a1 = __shfl((int)w1[1], slA, 64); F[1] = ghi ? a1 : a0; }
            { unsigned a0 = __shfl((int)w0[0], slB, 64), a1 = __shfl((int)w0[1], slB, 64); F[2] = ghi ? a1 : a0; }
            { unsigned a0 = __shfl((int)w1[0], slB, 64), a1 = __shfl((int)w1[1], slB, 64); F[3] = ghi ? a1 : a0; }
            pb[is] = __builtin_bit_cast(bf16x8, F);
        }

        __builtin_amdgcn_s_setprio(1);
        #pragma unroll
        for (int d = 0; d < 12; ++d) {
            bf16x8 vf = *(const bf16x8*)&L[12288u + (unsigned)(d * 512) + lane * 8];
            o[0][d] = MFMA16(vf, pb[0], o[0][d]);
            o[1][d] = MFMA16(vf, pb[1], o[1][d]);
        }
        __builtin_amdgcn_s_setprio(0);

        if (t + 1 < 32) {
            __syncthreads();
            cur ^= 1;
        }
    }

    // ---- epilogue: LDS transpose (row-stride 196 u16) -> coalesced stores ----
    __syncthreads();
    u16* LS = &lds[0][0];
    #pragma unroll
    for (int is = 0; is < 2; ++is) {
        const int row = (wl * 2 + is) * 16 + i;
        #pragma unroll
        for (int d = 0; d < 12; ++d) {
            u32x2 pk = { pack2(o[is][d][0], o[is][d][1]), pack2(o[is][d][2], o[is][d][3]) };
            *(u32x2*)&LS[row * 196 + d * 16 + g * 4] = pk;
        }
        if (g == 0) {
            const int ig = itile * 128 + row;
            float2 ml; ml.x = m_run[is]; ml.y = l_run[is];
            MLp[(size_t)half * 32768 + bh * 2048 + ig] = ml;
        }
    }
    __syncthreads();
    const int b2 = bh >> 3, hh = bh & 7;
    u16* P = half ? OpB : OpA;
    #pragma unroll
    for (int v = 0; v < 12; ++v) {
        const int Lx = v * 256 + tid;        // 0..3071
        const int ln   = Lx & 63;
        const int itql = (Lx >> 6) & 3;
        const int ksl  = (Lx >> 8) & 3;
        const int c    = Lx >> 10;           // 0..2
        const int i31 = ln & 31, b5 = ln >> 5;
        const int rowl = itql * 32 + i31;
        unsigned tv[8];
        #pragma unroll
        for (int e = 0; e < 8; ++e) {
            const int dd = ksl * 16 + b5 * 8 + e;
            tv[e] = LS[rowl * 196 + dd * 3 + c];
        }
        u32x4 pk = { tv[0] | (tv[1] << 16), tv[2] | (tv[3] << 16),
                     tv[4] | (tv[5] << 16), tv[6] | (tv[7] << 16) };
        size_t off = (((size_t)(b2 * 3 + c) * 32 + (hh * 4 + ksl)) * 64 + (itile * 4 + itql)) * 512
                     + (size_t)ln * 8;
        *(u32x4*)(P + off) = pk;
    }
}

// ---------------- K3: output projection + inline flash merge -----------------
// Merged O kept as single bf16 (drops O-lo term; delta ~1.4 << threshold);
// W stays split (presplit wohi/wolo). 2 MFMAs per (ks,c), merge VALU halved.
__global__ __launch_bounds__(256) void out_mfma(const u16* __restrict__ OpA,
                                                const u16* __restrict__ OpB,
                                                const float2* __restrict__ MLp,
                                                const u16* __restrict__ wohi,
                                                const u16* __restrict__ wolo,
                                                float* __restrict__ out) {
    const int tid = threadIdx.x, lane = tid & 63, w = tid >> 6, hf = lane >> 5, l31 = lane & 31;
    const int o0 = blockIdx.x * 32;
    const int n5 = blockIdx.y * 4 + w;
    const int b = blockIdx.z;
    const size_t wbase = (size_t)(o0 + l31) * 512 + hf * 8;

    float wa[8], wb[8], inv[8];
    #pragma unroll
    for (int hh = 0; hh < 8; ++hh) {
        size_t mi = (size_t)(b * 8 + hh) * 2048 + n5 * 32 + l31;
        float2 A = MLp[mi];
        float2 Bm = MLp[32768 + mi];
        float mm = fmaxf(A.x, Bm.x);
        wa[hh] = exp2f(A.x - mm);
        wb[hh] = exp2f(Bm.x - mm);
        inv[hh] = 1.0f / (A.y * wa[hh] + Bm.y * wb[hh]);
    }

    f32x16 acc[3] = {};
    #pragma unroll 2
    for (int ks = 0; ks < 32; ++ks) {
        const int hh = ks >> 2;
        const float waH = wa[hh], wbH = wb[hh], invH = inv[hh];
        bf16x8 wh = *(const bf16x8*)(wohi + wbase + ks * 16);
        bf16x8 wl = *(const bf16x8*)(wolo + wbase + ks * 16);
        #pragma unroll
        for (int c = 0; c < 3; ++c) {
            size_t pc = (size_t)(b * 3 + c) * 1048576 + (size_t)ks * 32768 + (size_t)n5 * 512 + (size_t)lane * 8;
            u32x4 aA = *(const u32x4*)(OpA + pc);
            u32x4 aB = *(const u32x4*)(OpB + pc);
            unsigned hiw[4];
            #pragma unroll
            for (int q = 0; q < 4; ++q) {
                u16 ua0 = (u16)(aA[q] & 0xffffu), ua1 = (u16)(aA[q] >> 16);
                u16 ub0 = (u16)(aB[q] & 0xffffu), ub1 = (u16)(aB[q] >> 16);
                float v0 = (fb16(ua0) * waH + fb16(ub0) * wbH) * invH;
                float v1 = (fb16(ua1) * waH + fb16(ub1) * wbH) * invH;
                hiw[q] = pack2(v0, v1);
            }
            union { bf16x8 v; u32x4 u; } H;
            H.u = { hiw[0], hiw[1], hiw[2], hiw[3] };
            acc[c] = MFMA(H.v, wh, acc[c]);
            acc[c] = MFMA(H.v, wl, acc[c]);
        }
    }
    #pragma unroll
    for (int r = 0; r < 16; ++r) {
        int n = (n5 << 5) + (r & 3) + 8 * (r >> 2) + 4 * hf;
        size_t off = ((size_t)(b * 2048 + n) * 256 + o0 + l31) * 3;
        out[off]     = acc[0][r];
        out[off + 1] = acc[1][r];
        out[off + 2] = acc[2][r];
    }
}

extern "C" void kernel_launch(void* const* d_in, const int* in_sizes, int n_in,
                              void* d_out, int out_size, void* d_ws, size_t ws_size,
                              hipStream_t stream) {
    const float* x     = (const float*)d_in[0];
    const float* w_qkv = (const float*)d_in[1];
    const float* w_out = (const float*)d_in[2];
    float* out = (float*)d_out;

    const size_t NB = (size_t)16 * 2048 * 192;       // 6.29M u16 per plane
    const size_t KVN = (size_t)16 * 64 * 18432;      // 18.87M u16 (37.7MB)
    u16* Qhi = (u16*)d_ws;
    u16* Qlo = Qhi + NB;
    u16* KVf = Qlo + NB;
    u16* OpA = KVf + KVN;                            // 12.6MB
    u16* OpB = OpA + NB;                             // 12.6MB
    float2* MLp = (float2*)(OpB + NB);               // 512KB
    u16* whi = (u16*)(MLp + 65536);                  // 0.79MB
    u16* wlo = whi + (size_t)1536 * 256;
    u16* wohi = wlo + (size_t)1536 * 256;            // 0.26MB
    u16* wolo = wohi + (size_t)256 * 512;

    presplitW<<<dim3(128), 256, 0, stream>>>(w_qkv, w_out, whi, wlo, wohi, wolo);
    qkv_mfma<<<dim3(768), 256, 0, stream>>>(x, whi, wlo, Qhi, Qlo, KVf);
    attn_mfma<<<dim3(512), 256, 0, stream>>>(Qhi, Qlo, KVf, OpA, OpB, MLp);
    out_mfma<<<dim3(8, 16, 2), 256, 0, stream>>>(OpA, OpB, MLp, wohi, wolo, out);
}

// Round 17
// 214.863 us; speedup vs baseline: 1.0909x; 1.0288x over previous
//
#include <hip/hip_runtime.h>
#include <hip/hip_bf16.h>

#define SCALE 0.07216878364870322f   // (3*64)^-0.5
#define LOG2E 1.4426950408889634f
// Q is pre-scaled by SCALE*LOG2E so attention logits are in log2 units.

typedef __bf16 bf16x8 __attribute__((ext_vector_type(8)));
typedef float f32x16 __attribute__((ext_vector_type(16)));
typedef float f32x4v __attribute__((ext_vector_type(4)));
typedef unsigned int u32x4 __attribute__((ext_vector_type(4)));
typedef unsigned int u32x2 __attribute__((ext_vector_type(2)));
typedef unsigned short u16;

#define MFMA(a, b, c) __builtin_amdgcn_mfma_f32_32x32x16_bf16(a, b, c, 0, 0, 0)
#define MFMA16(a, b, c) __builtin_amdgcn_mfma_f32_16x16x32_bf16(a, b, c, 0, 0, 0)

__device__ __forceinline__ u16 b16(float v) { return __builtin_bit_cast(u16, (__bf16)v); }
__device__ __forceinline__ float fb16(u16 u) {
    unsigned int t = (unsigned int)u << 16;
    return __builtin_bit_cast(float, t);
}
__device__ __forceinline__ unsigned int splitpack(float v) {
    u16 h = b16(v);
    float r = v - fb16(h);
    return (unsigned int)h | ((unsigned int)b16(r) << 16);
}
__device__ __forceinline__ unsigned int pack2(float a, float b) {
    return (unsigned int)b16(a) | ((unsigned int)b16(b) << 16);
}
__device__ __forceinline__ void gload16(const void* g, void* l) {
    __builtin_amdgcn_global_load_lds((const __attribute__((address_space(1))) void*)g,
                                     (__attribute__((address_space(3))) void*)l, 16, 0, 0);
}

// ---------------- K0: presplit x + weights into FRAG-MAJOR bf16 hi/lo --------
// x -> xfh/xfl: off = (((c*2+b)*64+nt)*16+k0)*512 + lane*8 + e
//   (lane = (n&31)|(khalf<<5), k = k0*16+khalf*8+e)  -- A-frag-major per c
// w_qkv -> wfh/wfl: off = (ot32*16+kc)*512 + lane*8 + e   (lane=(o&31)|(khalf<<5))
// w_out -> wofh/wofl: off = (ot32*32+ks)*512 + lane*8 + e
__global__ __launch_bounds__(256) void presplit(const float* __restrict__ x,
                                                const float* __restrict__ wq,
                                                const float* __restrict__ wo,
                                                u16* __restrict__ xfh, u16* __restrict__ xfl,
                                                u16* __restrict__ wfh, u16* __restrict__ wfl,
                                                u16* __restrict__ wofh, u16* __restrict__ wofl) {
    const int bid = blockIdx.x;
    const int tid = threadIdx.x;
    if (bid < 128) {                       // x: 64 nt x 2 b
        __shared__ float LT[32 * 49];      // 32 rows x 48 floats (+1 pad)
        const int nt = bid & 63, b = bid >> 6;
        const int n0 = nt * 32;
        const int lane = tid & 63;
        const int c = tid >> 6;            // 0..3 (c==3 idle in phase 2)
        for (int k0 = 0; k0 < 16; ++k0) {
            __syncthreads();
            #pragma unroll
            for (int s = 0; s < 2; ++s) {
                int v = tid + s * 256;
                if (v < 384) {
                    int row = v / 12, col4 = v % 12;
                    f32x4v t = *(const f32x4v*)(x + ((size_t)(b * 2048 + n0 + row)) * 768
                                                + k0 * 48 + col4 * 4);
                    *(f32x4v*)&LT[row * 49 + col4 * 4] = t;
                }
            }
            __syncthreads();
            if (c < 3) {
                const int nl = lane & 31, kh = lane >> 5;
                const float* src = &LT[nl * 49 + kh * 24 + c];
                bf16x8 hv, lv;
                #pragma unroll
                for (int e = 0; e < 8; ++e) {
                    float v = src[e * 3];
                    __bf16 hi = (__bf16)v;
                    hv[e] = hi;
                    lv[e] = (__bf16)(v - (float)hi);
                }
                size_t off = ((((size_t)(c * 2 + b) * 64 + nt) * 16 + k0) * 512) + lane * 8;
                *(bf16x8*)(xfh + off) = hv;
                *(bf16x8*)(xfl + off) = lv;
            }
        }
    } else if (bid < 176) {                // w_qkv: 48 ot32 tiles
        const int ot32 = bid - 128;
        const int lane = tid & 63;
        const int kc0 = tid >> 6;
        const int o = ot32 * 32 + (lane & 31);
        const int kh = lane >> 5;
        #pragma unroll
        for (int s = 0; s < 4; ++s) {
            const int kc = kc0 * 4 + s;
            const float* src = wq + (size_t)o * 256 + kc * 16 + kh * 8;
            bf16x8 hv, lv;
            #pragma unroll
            for (int e = 0; e < 8; ++e) {
                float v = src[e];
                __bf16 hi = (__bf16)v;
                hv[e] = hi;
                lv[e] = (__bf16)(v - (float)hi);
            }
            size_t off = ((size_t)(ot32 * 16 + kc) * 512) + lane * 8;
            *(bf16x8*)(wfh + off) = hv;
            *(bf16x8*)(wfl + off) = lv;
        }
    } else {                               // w_out: 8 ot32 tiles
        const int ot32 = bid - 176;
        const int lane = tid & 63;
        const int ks0 = tid >> 6;
        const int o = ot32 * 32 + (lane & 31);
        const int kh = lane >> 5;
        #pragma unroll
        for (int s = 0; s < 8; ++s) {
            const int ks = ks0 * 8 + s;
            const float* src = wo + (size_t)o * 512 + ks * 16 + kh * 8;
            bf16x8 hv, lv;
            #pragma unroll
            for (int e = 0; e < 8; ++e) {
                float v = src[e];
                __bf16 hi = (__bf16)v;
                hv[e] = hi;
                lv[e] = (__bf16)(v - (float)hi);
            }
            size_t off = ((size_t)(ot32 * 32 + ks) * 512) + lane * 8;
            *(bf16x8*)(wofh + off) = hv;
            *(bf16x8*)(wofl + off) = lv;
        }
    }
}

// ---------------- K1: QKV projection, ALL operands frag-major: pure MFMA -----
// Flat grid 768, XCD-remapped. Every hot-loop load is base + lane*8 (coalesced).
__global__ __launch_bounds__(256) void qkv_mfma(const u16* __restrict__ xfh,
                                                const u16* __restrict__ xfl,
                                                const u16* __restrict__ wfh,
                                                const u16* __restrict__ wfl,
                                                u16* __restrict__ Qhi, u16* __restrict__ Qlo,
                                                u16* __restrict__ KVf) {
    __shared__ unsigned int ldsr[2][32][196];
    const int tid = threadIdx.x;
    const int lane = tid & 63, w = tid >> 6, hf = lane >> 5, l31 = lane & 31;
    const int lq = lane & 15, gq = lane >> 4;
    const int id = blockIdx.x;           // 0..767
    const int xcd = id & 7;
    const int jj = id >> 3;              // 0..95
    const int nb = xcd * 4 + jj / 24;    // 0..31
    const int ot = jj % 24;              // 0..23
    const int o0 = ot * 64;
    const int b = nb >> 4;
    const int n0 = (nb & 15) * 128;
    const int nw0 = n0 + w * 32;
    const int part = o0 >> 9;
    const int h = (o0 >> 6) & 7;
    const int bh = b * 8 + h;
    const int nt = (nb & 15) * 4 + w;    // wave's 32-row tile

    const size_t xtb = (((size_t)b * 64 + nt) * 16) * 512 + lane * 8;  // + c*(2*64*16*512)
    const size_t cstride = (size_t)2 * 64 * 16 * 512;
    const size_t wtb0 = ((size_t)(o0 >> 5) * 16) * 512 + lane * 8;
    const size_t wtb1 = wtb0 + (size_t)16 * 512;

    f32x16 acc[3][2] = {};
    #pragma unroll 2
    for (int k0 = 0; k0 < 16; ++k0) {
        bf16x8 xh[3], xl[3], wh[2], wl[2];
        #pragma unroll
        for (int c = 0; c < 3; ++c) {
            xh[c] = *(const bf16x8*)(xfh + xtb + c * cstride + k0 * 512);
            xl[c] = *(const bf16x8*)(xfl + xtb + c * cstride + k0 * 512);
        }
        wh[0] = *(const bf16x8*)(wfh + wtb0 + k0 * 512);
        wl[0] = *(const bf16x8*)(wfl + wtb0 + k0 * 512);
        wh[1] = *(const bf16x8*)(wfh + wtb1 + k0 * 512);
        wl[1] = *(const bf16x8*)(wfl + wtb1 + k0 * 512);
        #pragma unroll
        for (int c = 0; c < 3; ++c)
            #pragma unroll
            for (int ot2 = 0; ot2 < 2; ++ot2) {
                acc[c][ot2] = MFMA(xh[c], wh[ot2], acc[c][ot2]);
                acc[c][ot2] = MFMA(xl[c], wh[ot2], acc[c][ot2]);
                acc[c][ot2] = MFMA(xh[c], wl[ot2], acc[c][ot2]);
            }
    }

    #pragma unroll
    for (int round = 0; round < 2; ++round) {
        __syncthreads();
        if ((w >> 1) == round) {
            unsigned int (*L)[196] = ldsr[w & 1];
            #pragma unroll
            for (int c = 0; c < 3; ++c)
                #pragma unroll
                for (int ot2 = 0; ot2 < 2; ++ot2)
                    #pragma unroll
                    for (int r = 0; r < 16; ++r) {
                        float v = acc[c][ot2][r];
                        if (part == 0) v *= (SCALE * LOG2E);
                        int nn = (r & 3) + 8 * (r >> 2) + 4 * hf;
                        int dcol = 3 * (ot2 * 32 + l31) + c;
                        L[nn][dcol] = (part == 2) ? (unsigned int)b16(v) : splitpack(v);
                    }
            if (part < 2) {
                #pragma unroll
                for (int is = 0; is < 2; ++is)
                    #pragma unroll
                    for (int kc = 0; kc < 6; ++kc) {
                        const unsigned int* p = &L[is * 16 + lq][kc * 32 + gq * 8];
                        u32x4 a = *(const u32x4*)p;
                        u32x4 bq = *(const u32x4*)(p + 4);
                        u32x4 hi = { (a[0] & 0xffffu) | (a[1] << 16), (a[2] & 0xffffu) | (a[3] << 16),
                                     (bq[0] & 0xffffu) | (bq[1] << 16), (bq[2] & 0xffffu) | (bq[3] << 16) };
                        u32x4 lo = { (a[0] >> 16) | (a[1] & 0xffff0000u), (a[2] >> 16) | (a[3] & 0xffff0000u),
                                     (bq[0] >> 16) | (bq[1] & 0xffff0000u), (bq[2] >> 16) | (bq[3] & 0xffff0000u) };
                        if (part == 0) {
                            size_t off = ((size_t)(bh * 128 + (nw0 >> 4) + is) * 6 + kc) * 512 + lane * 8;
                            *(u32x4*)(Qhi + off) = hi;
                            *(u32x4*)(Qlo + off) = lo;
                        } else {
                            size_t off = (size_t)(bh * 64 + (nw0 >> 5)) * 18432 + (is * 6 + kc) * 512 + lane * 8;
                            *(u32x4*)(KVf + off) = hi;
                            *(u32x4*)(KVf + off + 6144) = lo;
                        }
                    }
            } else {
                u16* vp = KVf + (size_t)(bh * 64 + (nw0 >> 5)) * 18432 + 12288 + lane * 8;
                #pragma unroll
                for (int d = 0; d < 12; ++d) {
                    unsigned int t[8];
                    #pragma unroll
                    for (int e = 0; e < 8; ++e)
                        t[e] = L[gq * 8 + e][d * 16 + lq];
                    u32x4 pk = { (t[0] & 0xffffu) | (t[1] << 16), (t[2] & 0xffffu) | (t[3] << 16),
                                 (t[4] & 0xffffu) | (t[5] << 16), (t[6] & 0xffffu) | (t[7] << 16) };
                    *(u32x4*)(vp + d * 512) = pk;
                }
            }
        }
    }
}

// ---------------- K2: MFMA flash attention (R14 verbatim) --------------------
__global__ __launch_bounds__(256, 2) void attn_mfma(
    const u16* __restrict__ Qhi, const u16* __restrict__ Qlo,
    const u16* __restrict__ KVf, u16* __restrict__ OpA, u16* __restrict__ OpB,
    float2* __restrict__ MLp) {
    __shared__ __align__(16) u16 lds[2][18432];  // per buf: Khi[6144]|Klo[6144]|V[6144]
    const int tid = threadIdx.x;
    const int lane = tid & 63;
    const int wl = tid >> 6;
    const int g = lane >> 4;
    const int i = lane & 15;
    const int id = blockIdx.x;                     // 0..511
    const int rem = id >> 3;
    const int grp = ((rem >> 4) << 3) | (id & 7);  // 0..31: (bh,half)
    const int itile = rem & 15;
    const int bh = grp >> 1;
    const int half = grp & 1;

    bf16x8 qh[2][6], ql[2][6];
    #pragma unroll
    for (int is = 0; is < 2; ++is) {
        size_t qb = (size_t)(bh * 128 + itile * 8 + wl * 2 + is) * 3072 + (size_t)lane * 8;
        #pragma unroll
        for (int kc = 0; kc < 6; ++kc) {
            qh[is][kc] = *(const bf16x8*)(Qhi + qb + kc * 512);
            ql[is][kc] = *(const bf16x8*)(Qlo + qb + kc * 512);
        }
    }

    const char* gKV = (const char*)KVf + (size_t)bh * 2359296;
    auto stage = [&](int buf, int jtAbs) {
        const char* src = gKV + (size_t)jtAbs * 36864;
        char* dst = (char*)&lds[buf][0];
        #pragma unroll
        for (int s = 0; s < 9; ++s) {
            const int c16 = (tid + s * 256) * 16;
            gload16(src + c16, dst + c16);
        }
    };

    const int jt0 = half * 32;
    stage(0, jt0);
    __syncthreads();
    int cur = 0;

    f32x4v o[2][12] = {};
    float m_run[2] = {-1e30f, -1e30f}, l_run[2] = {0.f, 0.f};

    for (int t = 0; t < 32; ++t) {
        if (t + 1 < 32) stage(cur ^ 1, jt0 + t + 1);
        const u16* L = &lds[cur][0];

        f32x4v s4[2][2] = {};
        __builtin_amdgcn_s_setprio(1);
        #pragma unroll
        for (int kc = 0; kc < 6; ++kc) {
            bf16x8 kh0 = *(const bf16x8*)&L[(unsigned)(kc * 512) + lane * 8];
            bf16x8 kh1 = *(const bf16x8*)&L[(unsigned)((6 + kc) * 512) + lane * 8];
            bf16x8 kl0 = *(const bf16x8*)&L[6144u + (unsigned)(kc * 512) + lane * 8];
            bf16x8 kl1 = *(const bf16x8*)&L[6144u + (unsigned)((6 + kc) * 512) + lane * 8];
            s4[0][0] = MFMA16(kh0, qh[0][kc], s4[0][0]);
            s4[0][1] = MFMA16(kh1, qh[0][kc], s4[0][1]);
            s4[1][0] = MFMA16(kh0, qh[1][kc], s4[1][0]);
            s4[1][1] = MFMA16(kh1, qh[1][kc], s4[1][1]);
            s4[0][0] = MFMA16(kh0, ql[0][kc], s4[0][0]);
            s4[0][1] = MFMA16(kh1, ql[0][kc], s4[0][1]);
            s4[1][0] = MFMA16(kh0, ql[1][kc], s4[1][0]);
            s4[1][1] = MFMA16(kh1, ql[1][kc], s4[1][1]);
            s4[0][0] = MFMA16(kl0, qh[0][kc], s4[0][0]);
            s4[0][1] = MFMA16(kl1, qh[0][kc], s4[0][1]);
            s4[1][0] = MFMA16(kl0, qh[1][kc], s4[1][0]);
            s4[1][1] = MFMA16(kl1, qh[1][kc], s4[1][1]);
        }
        __builtin_amdgcn_s_setprio(0);

        bf16x8 pb[2];
        #pragma unroll
        for (int is = 0; is < 2; ++is) {
            float pm = -1e30f;
            #pragma unroll
            for (int js = 0; js < 2; ++js)
                #pragma unroll
                for (int r = 0; r < 4; ++r) pm = fmaxf(pm, s4[is][js][r]);
            pm = fmaxf(pm, __shfl_xor(pm, 16, 64));
            pm = fmaxf(pm, __shfl_xor(pm, 32, 64));
            if (!__all(pm <= m_run[is] + 8.0f)) {   // T13 defer-rescale
                float mnew = fmaxf(m_run[is], pm);
                float sc = exp2f(m_run[is] - mnew);
                l_run[is] *= sc;
                #pragma unroll
                for (int d = 0; d < 12; ++d) o[is][d] = o[is][d] * sc;
                m_run[is] = mnew;
            }
            float rs = 0.f;
            unsigned int w0[2], w1[2];
            #pragma unroll
            for (int js = 0; js < 2; ++js) {
                float p0 = exp2f(s4[is][js][0] - m_run[is]), p1 = exp2f(s4[is][js][1] - m_run[is]);
                float p2 = exp2f(s4[is][js][2] - m_run[is]), p3 = exp2f(s4[is][js][3] - m_run[is]);
                rs += (p0 + p1) + (p2 + p3);
                w0[js] = pack2(p0, p1);
                w1[js] = pack2(p2, p3);
            }
            rs += __shfl_xor(rs, 16, 64);
            rs += __shfl_xor(rs, 32, 64);
            l_run[is] += rs;

            u32x4 F;
            const int slA = ((g & 1) << 5) + i;
            const int slB = slA + 16;
            const bool ghi = (g >> 1) != 0;
            { unsigned a0 = __shfl((int)w0[0], slA, 64), a1 = __shfl((int)w0[1], slA, 64); F[0] = ghi ? a1 : a0; }
            { unsigned a0 = __shfl((int)w1[0], slA, 64), a1 = __shfl((int)w1[1], slA, 64); F[1] = ghi ? a1 : a0; }
            { unsigned a0 = __shfl((int)w0[0], slB, 64), a1 = __shfl((int)w0[1], slB, 64); F[2] = ghi ? a1 : a0; }
            { unsigned a0 = __shfl((int)w1[0], slB, 64), a1 = __shfl((int)w1[1], slB, 64); F[3] = ghi ? a1 : a0; }
            pb[is] = __builtin_bit_cast(bf16x8, F);
        }

        __builtin_amdgcn_s_setprio(1);
        #pragma unroll
        for (int d = 0; d < 12; ++d) {
            bf16x8 vf = *(const bf16x8*)&L[12288u + (unsigned)(d * 512) + lane * 8];
            o[0][d] = MFMA16(vf, pb[0], o[0][d]);
            o[1][d] = MFMA16(vf, pb[1], o[1][d]);
        }
        __builtin_amdgcn_s_setprio(0);

        if (t + 1 < 32) {
            __syncthreads();
            cur ^= 1;
        }
    }

    // ---- epilogue: LDS transpose (row-stride 196 u16) -> coalesced stores ----
    __syncthreads();
    u16* LS = &lds[0][0];
    #pragma unroll
    for (int is = 0; is < 2; ++is) {
        const int row = (wl * 2 + is) * 16 + i;
        #pragma unroll
        for (int d = 0; d < 12; ++d) {
            u32x2 pk = { pack2(o[is][d][0], o[is][d][1]), pack2(o[is][d][2], o[is][d][3]) };
            *(u32x2*)&LS[row * 196 + d * 16 + g * 4] = pk;
        }
        if (g == 0) {
            const int ig = itile * 128 + row;
            float2 ml; ml.x = m_run[is]; ml.y = l_run[is];
            MLp[(size_t)half * 32768 + bh * 2048 + ig] = ml;
        }
    }
    __syncthreads();
    const int b2 = bh >> 3, hh = bh & 7;
    u16* P = half ? OpB : OpA;
    #pragma unroll
    for (int v = 0; v < 12; ++v) {
        const int Lx = v * 256 + tid;
        const int ln   = Lx & 63;
        const int itql = (Lx >> 6) & 3;
        const int ksl  = (Lx >> 8) & 3;
        const int c    = Lx >> 10;
        const int i31 = ln & 31, b5 = ln >> 5;
        const int rowl = itql * 32 + i31;
        unsigned tv[8];
        #pragma unroll
        for (int e = 0; e < 8; ++e) {
            const int dd = ksl * 16 + b5 * 8 + e;
            tv[e] = LS[rowl * 196 + dd * 3 + c];
        }
        u32x4 pk = { tv[0] | (tv[1] << 16), tv[2] | (tv[3] << 16),
                     tv[4] | (tv[5] << 16), tv[6] | (tv[7] << 16) };
        size_t off = (((size_t)(b2 * 3 + c) * 32 + (hh * 4 + ksl)) * 64 + (itile * 4 + itql)) * 512
                     + (size_t)ln * 8;
        *(u32x4*)(P + off) = pk;
    }
}

// ---------------- K3: output projection + inline flash merge -----------------
// W frag-major (coalesced); merged O single bf16; 2 MFMAs per (ks,c).
__global__ __launch_bounds__(256) void out_mfma(const u16* __restrict__ OpA,
                                                const u16* __restrict__ OpB,
                                                const float2* __restrict__ MLp,
                                                const u16* __restrict__ wofh,
                                                const u16* __restrict__ wofl,
                                                float* __restrict__ out) {
    const int tid = threadIdx.x, lane = tid & 63, w = tid >> 6, hf = lane >> 5, l31 = lane & 31;
    const int o0 = blockIdx.x * 32;
    const int n5 = blockIdx.y * 4 + w;
    const int b = blockIdx.z;
    const size_t wtb = ((size_t)blockIdx.x * 32) * 512 + lane * 8;

    float wa[8], wb[8], inv[8];
    #pragma unroll
    for (int hh = 0; hh < 8; ++hh) {
        size_t mi = (size_t)(b * 8 + hh) * 2048 + n5 * 32 + l31;
        float2 A = MLp[mi];
        float2 Bm = MLp[32768 + mi];
        float mm = fmaxf(A.x, Bm.x);
        wa[hh] = exp2f(A.x - mm);
        wb[hh] = exp2f(Bm.x - mm);
        inv[hh] = 1.0f / (A.y * wa[hh] + Bm.y * wb[hh]);
    }

    f32x16 acc[3] = {};
    #pragma unroll 2
    for (int ks = 0; ks < 32; ++ks) {
        const int hh = ks >> 2;
        const float waH = wa[hh], wbH = wb[hh], invH = inv[hh];
        bf16x8 wh = *(const bf16x8*)(wofh + wtb + ks * 512);
        bf16x8 wl = *(const bf16x8*)(wofl + wtb + ks * 512);
        #pragma unroll
        for (int c = 0; c < 3; ++c) {
            size_t pc = (size_t)(b * 3 + c) * 1048576 + (size_t)ks * 32768 + (size_t)n5 * 512 + (size_t)lane * 8;
            u32x4 aA = *(const u32x4*)(OpA + pc);
            u32x4 aB = *(const u32x4*)(OpB + pc);
            unsigned hiw[4];
            #pragma unroll
            for (int q = 0; q < 4; ++q) {
                u16 ua0 = (u16)(aA[q] & 0xffffu), ua1 = (u16)(aA[q] >> 16);
                u16 ub0 = (u16)(aB[q] & 0xffffu), ub1 = (u16)(aB[q] >> 16);
                float v0 = (fb16(ua0) * waH + fb16(ub0) * wbH) * invH;
                float v1 = (fb16(ua1) * waH + fb16(ub1) * wbH) * invH;
                hiw[q] = pack2(v0, v1);
            }
            union { bf16x8 v; u32x4 u; } H;
            H.u = { hiw[0], hiw[1], hiw[2], hiw[3] };
            acc[c] = MFMA(H.v, wh, acc[c]);
            acc[c] = MFMA(H.v, wl, acc[c]);
        }
    }
    #pragma unroll
    for (int r = 0; r < 16; ++r) {
        int n = (n5 << 5) + (r & 3) + 8 * (r >> 2) + 4 * hf;
        size_t off = ((size_t)(b * 2048 + n) * 256 + o0 + l31) * 3;
        out[off]     = acc[0][r];
        out[off + 1] = acc[1][r];
        out[off + 2] = acc[2][r];
    }
}

extern "C" void kernel_launch(void* const* d_in, const int* in_sizes, int n_in,
                              void* d_out, int out_size, void* d_ws, size_t ws_size,
                              hipStream_t stream) {
    const float* x     = (const float*)d_in[0];
    const float* w_qkv = (const float*)d_in[1];
    const float* w_out = (const float*)d_in[2];
    float* out = (float*)d_out;

    const size_t NB = (size_t)16 * 2048 * 192;       // 6.29M u16 per plane
    const size_t KVN = (size_t)16 * 64 * 18432;      // 18.87M u16
    const size_t XF = (size_t)3 * 2 * 64 * 16 * 512; // 3.15M u16 per x plane
    u16* Qhi = (u16*)d_ws;
    u16* Qlo = Qhi + NB;
    u16* KVf = Qlo + NB;
    u16* OpA = KVf + KVN;
    u16* OpB = OpA + NB;
    float2* MLp = (float2*)(OpB + NB);               // 512KB
    u16* xfh = (u16*)(MLp + 65536);
    u16* xfl = xfh + XF;
    u16* wfh = xfl + XF;                             // 393216 u16
    u16* wfl = wfh + (size_t)1536 * 256;
    u16* wofh = wfl + (size_t)1536 * 256;            // 131072 u16
    u16* wofl = wofh + (size_t)256 * 512;

    presplit<<<dim3(184), 256, 0, stream>>>(x, w_qkv, w_out, xfh, xfl, wfh, wfl, wofh, wofl);
    qkv_mfma<<<dim3(768), 256, 0, stream>>>(xfh, xfl, wfh, wfl, Qhi, Qlo, KVf);
    attn_mfma<<<dim3(512), 256, 0, stream>>>(Qhi, Qlo, KVf, OpA, OpB, MLp);
    out_mfma<<<dim3(8, 16, 2), 256, 0, stream>>>(OpA, OpB, MLp, wofh, wofl, out);
}

// Round 18
// 210.226 us; speedup vs baseline: 1.1150x; 1.0221x over previous
//
#include <hip/hip_runtime.h>
#include <hip/hip_bf16.h>

#define SCALE 0.07216878364870322f   // (3*64)^-0.5
#define LOG2E 1.4426950408889634f
// Q is pre-scaled by SCALE*LOG2E so attention logits are in log2 units.

typedef __bf16 bf16x8 __attribute__((ext_vector_type(8)));
typedef float f32x16 __attribute__((ext_vector_type(16)));
typedef float f32x4v __attribute__((ext_vector_type(4)));
typedef unsigned int u32x4 __attribute__((ext_vector_type(4)));
typedef unsigned int u32x2 __attribute__((ext_vector_type(2)));
typedef unsigned short u16;

#define MFMA(a, b, c) __builtin_amdgcn_mfma_f32_32x32x16_bf16(a, b, c, 0, 0, 0)
#define MFMA16(a, b, c) __builtin_amdgcn_mfma_f32_16x16x32_bf16(a, b, c, 0, 0, 0)

__device__ __forceinline__ u16 b16(float v) { return __builtin_bit_cast(u16, (__bf16)v); }
__device__ __forceinline__ float fb16(u16 u) {
    unsigned int t = (unsigned int)u << 16;
    return __builtin_bit_cast(float, t);
}
__device__ __forceinline__ unsigned int splitpack(float v) {
    u16 h = b16(v);
    float r = v - fb16(h);
    return (unsigned int)h | ((unsigned int)b16(r) << 16);
}
__device__ __forceinline__ unsigned int pack2(float a, float b) {
    return (unsigned int)b16(a) | ((unsigned int)b16(b) << 16);
}
__device__ __forceinline__ void gload16(const void* g, void* l) {
    __builtin_amdgcn_global_load_lds((const __attribute__((address_space(1))) void*)g,
                                     (__attribute__((address_space(3))) void*)l, 16, 0, 0);
}

// ---------------- K0: presplit x + weights into FRAG-MAJOR bf16 hi/lo --------
// x part: 512 blocks (64 nt x 2 b x 4 k0-groups), 4 k0 iterations each.
// w_qkv: blocks 512..559; w_out: blocks 560..567.
__global__ __launch_bounds__(256) void presplit(const float* __restrict__ x,
                                                const float* __restrict__ wq,
                                                const float* __restrict__ wo,
                                                u16* __restrict__ xfh, u16* __restrict__ xfl,
                                                u16* __restrict__ wfh, u16* __restrict__ wfl,
                                                u16* __restrict__ wofh, u16* __restrict__ wofl) {
    const int bid = blockIdx.x;
    const int tid = threadIdx.x;
    if (bid < 512) {                       // x: 64 nt x 2 b x 4 k0g
        __shared__ float LT[32 * 49];
        const int nt = bid & 63, b = (bid >> 6) & 1, k0g = bid >> 7;
        const int n0 = nt * 32;
        const int lane = tid & 63;
        const int c = tid >> 6;            // 0..3 (c==3 idle in phase 2)
        for (int k0 = k0g * 4; k0 < k0g * 4 + 4; ++k0) {
            __syncthreads();
            #pragma unroll
            for (int s = 0; s < 2; ++s) {
                int v = tid + s * 256;
                if (v < 384) {
                    int row = v / 12, col4 = v % 12;
                    f32x4v t = *(const f32x4v*)(x + ((size_t)(b * 2048 + n0 + row)) * 768
                                                + k0 * 48 + col4 * 4);
                    *(f32x4v*)&LT[row * 49 + col4 * 4] = t;
                }
            }
            __syncthreads();
            if (c < 3) {
                const int nl = lane & 31, kh = lane >> 5;
                const float* src = &LT[nl * 49 + kh * 24 + c];
                bf16x8 hv, lv;
                #pragma unroll
                for (int e = 0; e < 8; ++e) {
                    float v = src[e * 3];
                    __bf16 hi = (__bf16)v;
                    hv[e] = hi;
                    lv[e] = (__bf16)(v - (float)hi);
                }
                size_t off = ((((size_t)(c * 2 + b) * 64 + nt) * 16 + k0) * 512) + lane * 8;
                *(bf16x8*)(xfh + off) = hv;
                *(bf16x8*)(xfl + off) = lv;
            }
        }
    } else if (bid < 560) {                // w_qkv: 48 ot32 tiles
        const int ot32 = bid - 512;
        const int lane = tid & 63;
        const int kc0 = tid >> 6;
        const int o = ot32 * 32 + (lane & 31);
        const int kh = lane >> 5;
        #pragma unroll
        for (int s = 0; s < 4; ++s) {
            const int kc = kc0 * 4 + s;
            const float* src = wq + (size_t)o * 256 + kc * 16 + kh * 8;
            bf16x8 hv, lv;
            #pragma unroll
            for (int e = 0; e < 8; ++e) {
                float v = src[e];
                __bf16 hi = (__bf16)v;
                hv[e] = hi;
                lv[e] = (__bf16)(v - (float)hi);
            }
            size_t off = ((size_t)(ot32 * 16 + kc) * 512) + lane * 8;
            *(bf16x8*)(wfh + off) = hv;
            *(bf16x8*)(wfl + off) = lv;
        }
    } else {                               // w_out: 8 ot32 tiles
        const int ot32 = bid - 560;
        const int lane = tid & 63;
        const int ks0 = tid >> 6;
        const int o = ot32 * 32 + (lane & 31);
        const int kh = lane >> 5;
        #pragma unroll
        for (int s = 0; s < 8; ++s) {
            const int ks = ks0 * 8 + s;
            const float* src = wo + (size_t)o * 512 + ks * 16 + kh * 8;
            bf16x8 hv, lv;
            #pragma unroll
            for (int e = 0; e < 8; ++e) {
                float v = src[e];
                __bf16 hi = (__bf16)v;
                hv[e] = hi;
                lv[e] = (__bf16)(v - (float)hi);
            }
            size_t off = ((size_t)(ot32 * 32 + ks) * 512) + lane * 8;
            *(bf16x8*)(wofh + off) = hv;
            *(bf16x8*)(wofl + off) = lv;
        }
    }
}

// ---------------- K1: QKV projection, ALL operands frag-major: pure MFMA -----
__global__ __launch_bounds__(256) void qkv_mfma(const u16* __restrict__ xfh,
                                                const u16* __restrict__ xfl,
                                                const u16* __restrict__ wfh,
                                                const u16* __restrict__ wfl,
                                                u16* __restrict__ Qhi, u16* __restrict__ Qlo,
                                                u16* __restrict__ KVf) {
    __shared__ unsigned int ldsr[2][32][196];
    const int tid = threadIdx.x;
    const int lane = tid & 63, w = tid >> 6, hf = lane >> 5, l31 = lane & 31;
    const int lq = lane & 15, gq = lane >> 4;
    const int id = blockIdx.x;           // 0..767
    const int xcd = id & 7;
    const int jj = id >> 3;              // 0..95
    const int nb = xcd * 4 + jj / 24;    // 0..31
    const int ot = jj % 24;              // 0..23
    const int o0 = ot * 64;
    const int b = nb >> 4;
    const int n0 = (nb & 15) * 128;
    const int nw0 = n0 + w * 32;
    const int part = o0 >> 9;
    const int h = (o0 >> 6) & 7;
    const int bh = b * 8 + h;
    const int nt = (nb & 15) * 4 + w;

    const size_t xtb = (((size_t)b * 64 + nt) * 16) * 512 + lane * 8;
    const size_t cstride = (size_t)2 * 64 * 16 * 512;
    const size_t wtb0 = ((size_t)(o0 >> 5) * 16) * 512 + lane * 8;
    const size_t wtb1 = wtb0 + (size_t)16 * 512;

    f32x16 acc[3][2] = {};
    #pragma unroll 2
    for (int k0 = 0; k0 < 16; ++k0) {
        bf16x8 xh[3], xl[3], wh[2], wl[2];
        #pragma unroll
        for (int c = 0; c < 3; ++c) {
            xh[c] = *(const bf16x8*)(xfh + xtb + c * cstride + k0 * 512);
            xl[c] = *(const bf16x8*)(xfl + xtb + c * cstride + k0 * 512);
        }
        wh[0] = *(const bf16x8*)(wfh + wtb0 + k0 * 512);
        wl[0] = *(const bf16x8*)(wfl + wtb0 + k0 * 512);
        wh[1] = *(const bf16x8*)(wfh + wtb1 + k0 * 512);
        wl[1] = *(const bf16x8*)(wfl + wtb1 + k0 * 512);
        #pragma unroll
        for (int c = 0; c < 3; ++c)
            #pragma unroll
            for (int ot2 = 0; ot2 < 2; ++ot2) {
                acc[c][ot2] = MFMA(xh[c], wh[ot2], acc[c][ot2]);
                acc[c][ot2] = MFMA(xl[c], wh[ot2], acc[c][ot2]);
                acc[c][ot2] = MFMA(xh[c], wl[ot2], acc[c][ot2]);
            }
    }

    #pragma unroll
    for (int round = 0; round < 2; ++round) {
        __syncthreads();
        if ((w >> 1) == round) {
            unsigned int (*L)[196] = ldsr[w & 1];
            #pragma unroll
            for (int c = 0; c < 3; ++c)
                #pragma unroll
                for (int ot2 = 0; ot2 < 2; ++ot2)
                    #pragma unroll
                    for (int r = 0; r < 16; ++r) {
                        float v = acc[c][ot2][r];
                        if (part == 0) v *= (SCALE * LOG2E);
                        int nn = (r & 3) + 8 * (r >> 2) + 4 * hf;
                        int dcol = 3 * (ot2 * 32 + l31) + c;
                        L[nn][dcol] = (part == 2) ? (unsigned int)b16(v) : splitpack(v);
                    }
            if (part < 2) {
                #pragma unroll
                for (int is = 0; is < 2; ++is)
                    #pragma unroll
                    for (int kc = 0; kc < 6; ++kc) {
                        const unsigned int* p = &L[is * 16 + lq][kc * 32 + gq * 8];
                        u32x4 a = *(const u32x4*)p;
                        u32x4 bq = *(const u32x4*)(p + 4);
                        u32x4 hi = { (a[0] & 0xffffu) | (a[1] << 16), (a[2] & 0xffffu) | (a[3] << 16),
                                     (bq[0] & 0xffffu) | (bq[1] << 16), (bq[2] & 0xffffu) | (bq[3] << 16) };
                        u32x4 lo = { (a[0] >> 16) | (a[1] & 0xffff0000u), (a[2] >> 16) | (a[3] & 0xffff0000u),
                                     (bq[0] >> 16) | (bq[1] & 0xffff0000u), (bq[2] >> 16) | (bq[3] & 0xffff0000u) };
                        if (part == 0) {
                            size_t off = ((size_t)(bh * 128 + (nw0 >> 4) + is) * 6 + kc) * 512 + lane * 8;
                            *(u32x4*)(Qhi + off) = hi;
                            *(u32x4*)(Qlo + off) = lo;
                        } else {
                            size_t off = (size_t)(bh * 64 + (nw0 >> 5)) * 18432 + (is * 6 + kc) * 512 + lane * 8;
                            *(u32x4*)(KVf + off) = hi;
                            *(u32x4*)(KVf + off + 6144) = lo;
                        }
                    }
            } else {
                u16* vp = KVf + (size_t)(bh * 64 + (nw0 >> 5)) * 18432 + 12288 + lane * 8;
                #pragma unroll
                for (int d = 0; d < 12; ++d) {
                    unsigned int t[8];
                    #pragma unroll
                    for (int e = 0; e < 8; ++e)
                        t[e] = L[gq * 8 + e][d * 16 + lq];
                    u32x4 pk = { (t[0] & 0xffffu) | (t[1] << 16), (t[2] & 0xffffu) | (t[3] << 16),
                                 (t[4] & 0xffffu) | (t[5] << 16), (t[6] & 0xffffu) | (t[7] << 16) };
                    *(u32x4*)(vp + d * 512) = pk;
                }
            }
        }
    }
}

// ---------------- K2: MFMA flash attention (R14 verbatim) --------------------
__global__ __launch_bounds__(256, 2) void attn_mfma(
    const u16* __restrict__ Qhi, const u16* __restrict__ Qlo,
    const u16* __restrict__ KVf, u16* __restrict__ OpA, u16* __restrict__ OpB,
    float2* __restrict__ MLp) {
    __shared__ __align__(16) u16 lds[2][18432];  // per buf: Khi[6144]|Klo[6144]|V[6144]
    const int tid = threadIdx.x;
    const int lane = tid & 63;
    const int wl = tid >> 6;
    const int g = lane >> 4;
    const int i = lane & 15;
    const int id = blockIdx.x;                     // 0..511
    const int rem = id >> 3;
    const int grp = ((rem >> 4) << 3) | (id & 7);  // 0..31: (bh,half)
    const int itile = rem & 15;
    const int bh = grp >> 1;
    const int half = grp & 1;

    bf16x8 qh[2][6], ql[2][6];
    #pragma unroll
    for (int is = 0; is < 2; ++is) {
        size_t qb = (size_t)(bh * 128 + itile * 8 + wl * 2 + is) * 3072 + (size_t)lane * 8;
        #pragma unroll
        for (int kc = 0; kc < 6; ++kc) {
            qh[is][kc] = *(const bf16x8*)(Qhi + qb + kc * 512);
            ql[is][kc] = *(const bf16x8*)(Qlo + qb + kc * 512);
        }
    }

    const char* gKV = (const char*)KVf + (size_t)bh * 2359296;
    auto stage = [&](int buf, int jtAbs) {
        const char* src = gKV + (size_t)jtAbs * 36864;
        char* dst = (char*)&lds[buf][0];
        #pragma unroll
        for (int s = 0; s < 9; ++s) {
            const int c16 = (tid + s * 256) * 16;
            gload16(src + c16, dst + c16);
        }
    };

    const int jt0 = half * 32;
    stage(0, jt0);
    __syncthreads();
    int cur = 0;

    f32x4v o[2][12] = {};
    float m_run[2] = {-1e30f, -1e30f}, l_run[2] = {0.f, 0.f};

    for (int t = 0; t < 32; ++t) {
        if (t + 1 < 32) stage(cur ^ 1, jt0 + t + 1);
        const u16* L = &lds[cur][0];

        f32x4v s4[2][2] = {};
        __builtin_amdgcn_s_setprio(1);
        #pragma unroll
        for (int kc = 0; kc < 6; ++kc) {
            bf16x8 kh0 = *(const bf16x8*)&L[(unsigned)(kc * 512) + lane * 8];
            bf16x8 kh1 = *(const bf16x8*)&L[(unsigned)((6 + kc) * 512) + lane * 8];
            bf16x8 kl0 = *(const bf16x8*)&L[6144u + (unsigned)(kc * 512) + lane * 8];
            bf16x8 kl1 = *(const bf16x8*)&L[6144u + (unsigned)((6 + kc) * 512) + lane * 8];
            s4[0][0] = MFMA16(kh0, qh[0][kc], s4[0][0]);
            s4[0][1] = MFMA16(kh1, qh[0][kc], s4[0][1]);
            s4[1][0] = MFMA16(kh0, qh[1][kc], s4[1][0]);
            s4[1][1] = MFMA16(kh1, qh[1][kc], s4[1][1]);
            s4[0][0] = MFMA16(kh0, ql[0][kc], s4[0][0]);
            s4[0][1] = MFMA16(kh1, ql[0][kc], s4[0][1]);
            s4[1][0] = MFMA16(kh0, ql[1][kc], s4[1][0]);
            s4[1][1] = MFMA16(kh1, ql[1][kc], s4[1][1]);
            s4[0][0] = MFMA16(kl0, qh[0][kc], s4[0][0]);
            s4[0][1] = MFMA16(kl1, qh[0][kc], s4[0][1]);
            s4[1][0] = MFMA16(kl0, qh[1][kc], s4[1][0]);
            s4[1][1] = MFMA16(kl1, qh[1][kc], s4[1][1]);
        }
        __builtin_amdgcn_s_setprio(0);

        bf16x8 pb[2];
        #pragma unroll
        for (int is = 0; is < 2; ++is) {
            float pm = -1e30f;
            #pragma unroll
            for (int js = 0; js < 2; ++js)
                #pragma unroll
                for (int r = 0; r < 4; ++r) pm = fmaxf(pm, s4[is][js][r]);
            pm = fmaxf(pm, __shfl_xor(pm, 16, 64));
            pm = fmaxf(pm, __shfl_xor(pm, 32, 64));
            if (!__all(pm <= m_run[is] + 8.0f)) {   // T13 defer-rescale
                float mnew = fmaxf(m_run[is], pm);
                float sc = exp2f(m_run[is] - mnew);
                l_run[is] *= sc;
                #pragma unroll
                for (int d = 0; d < 12; ++d) o[is][d] = o[is][d] * sc;
                m_run[is] = mnew;
            }
            float rs = 0.f;
            unsigned int w0[2], w1[2];
            #pragma unroll
            for (int js = 0; js < 2; ++js) {
                float p0 = exp2f(s4[is][js][0] - m_run[is]), p1 = exp2f(s4[is][js][1] - m_run[is]);
                float p2 = exp2f(s4[is][js][2] - m_run[is]), p3 = exp2f(s4[is][js][3] - m_run[is]);
                rs += (p0 + p1) + (p2 + p3);
                w0[js] = pack2(p0, p1);
                w1[js] = pack2(p2, p3);
            }
            rs += __shfl_xor(rs, 16, 64);
            rs += __shfl_xor(rs, 32, 64);
            l_run[is] += rs;

            u32x4 F;
            const int slA = ((g & 1) << 5) + i;
            const int slB = slA + 16;
            const bool ghi = (g >> 1) != 0;
            { unsigned a0 = __shfl((int)w0[0], slA, 64), a1 = __shfl((int)w0[1], slA, 64); F[0] = ghi ? a1 : a0; }
            { unsigned a0 = __shfl((int)w1[0], slA, 64), a1 = __shfl((int)w1[1], slA, 64); F[1] = ghi ? a1 : a0; }
            { unsigned a0 = __shfl((int)w0[0], slB, 64), a1 = __shfl((int)w0[1], slB, 64); F[2] = ghi ? a1 : a0; }
            { unsigned a0 = __shfl((int)w1[0], slB, 64), a1 = __shfl((int)w1[1], slB, 64); F[3] = ghi ? a1 : a0; }
            pb[is] = __builtin_bit_cast(bf16x8, F);
        }

        __builtin_amdgcn_s_setprio(1);
        #pragma unroll
        for (int d = 0; d < 12; ++d) {
            bf16x8 vf = *(const bf16x8*)&L[12288u + (unsigned)(d * 512) + lane * 8];
            o[0][d] = MFMA16(vf, pb[0], o[0][d]);
            o[1][d] = MFMA16(vf, pb[1], o[1][d]);
        }
        __builtin_amdgcn_s_setprio(0);

        if (t + 1 < 32) {
            __syncthreads();
            cur ^= 1;
        }
    }

    // ---- epilogue: LDS transpose (row-stride 196 u16) -> coalesced stores ----
    __syncthreads();
    u16* LS = &lds[0][0];
    #pragma unroll
    for (int is = 0; is < 2; ++is) {
        const int row = (wl * 2 + is) * 16 + i;
        #pragma unroll
        for (int d = 0; d < 12; ++d) {
            u32x2 pk = { pack2(o[is][d][0], o[is][d][1]), pack2(o[is][d][2], o[is][d][3]) };
            *(u32x2*)&LS[row * 196 + d * 16 + g * 4] = pk;
        }
        if (g == 0) {
            const int ig = itile * 128 + row;
            float2 ml; ml.x = m_run[is]; ml.y = l_run[is];
            MLp[(size_t)half * 32768 + bh * 2048 + ig] = ml;
        }
    }
    __syncthreads();
    const int b2 = bh >> 3, hh = bh & 7;
    u16* P = half ? OpB : OpA;
    #pragma unroll
    for (int v = 0; v < 12; ++v) {
        const int Lx = v * 256 + tid;
        const int ln   = Lx & 63;
        const int itql = (Lx >> 6) & 3;
        const int ksl  = (Lx >> 8) & 3;
        const int c    = Lx >> 10;
        const int i31 = ln & 31, b5 = ln >> 5;
        const int rowl = itql * 32 + i31;
        unsigned tv[8];
        #pragma unroll
        for (int e = 0; e < 8; ++e) {
            const int dd = ksl * 16 + b5 * 8 + e;
            tv[e] = LS[rowl * 196 + dd * 3 + c];
        }
        u32x4 pk = { tv[0] | (tv[1] << 16), tv[2] | (tv[3] << 16),
                     tv[4] | (tv[5] << 16), tv[6] | (tv[7] << 16) };
        size_t off = (((size_t)(b2 * 3 + c) * 32 + (hh * 4 + ksl)) * 64 + (itile * 4 + itql)) * 512
                     + (size_t)ln * 8;
        *(u32x4*)(P + off) = pk;
    }
}

// ---------------- K3: output projection + inline flash merge, c-split grid ---
// Flat grid 768: c = id>>8 (c-siblings share an XCD: 256 % 8 == 0), r = id&255
// encodes (o-tile, n-tile, b). 3 blocks/CU -> 3 waves/SIMD; per-ks VALU /3.
__global__ __launch_bounds__(256) void out_mfma(const u16* __restrict__ OpA,
                                                const u16* __restrict__ OpB,
                                                const float2* __restrict__ MLp,
                                                const u16* __restrict__ wofh,
                                                const u16* __restrict__ wofl,
                                                float* __restrict__ out) {
    const int tid = threadIdx.x, lane = tid & 63, w = tid >> 6, hf = lane >> 5, l31 = lane & 31;
    const int id = blockIdx.x;
    const int c = id >> 8;          // 0..2
    const int r5 = id & 255;
    const int xo = r5 & 7;          // 8 o-tiles of 32
    const int yy = (r5 >> 3) & 15;  // 16 n-tiles
    const int b = r5 >> 7;
    const int o0 = xo * 32;
    const int n5 = yy * 4 + w;
    const size_t wtb = ((size_t)xo * 32) * 512 + lane * 8;

    float wa[8], wb[8], inv[8];
    #pragma unroll
    for (int hh = 0; hh < 8; ++hh) {
        size_t mi = (size_t)(b * 8 + hh) * 2048 + n5 * 32 + l31;
        float2 A = MLp[mi];
        float2 Bm = MLp[32768 + mi];
        float mm = fmaxf(A.x, Bm.x);
        wa[hh] = exp2f(A.x - mm);
        wb[hh] = exp2f(Bm.x - mm);
        inv[hh] = 1.0f / (A.y * wa[hh] + Bm.y * wb[hh]);
    }

    f32x16 acc = {};
    #pragma unroll 2
    for (int ks = 0; ks < 32; ++ks) {
        const int hh = ks >> 2;
        const float waH = wa[hh], wbH = wb[hh], invH = inv[hh];
        bf16x8 wh = *(const bf16x8*)(wofh + wtb + ks * 512);
        bf16x8 wl = *(const bf16x8*)(wofl + wtb + ks * 512);
        size_t pc = (size_t)(b * 3 + c) * 1048576 + (size_t)ks * 32768 + (size_t)n5 * 512 + (size_t)lane * 8;
        u32x4 aA = *(const u32x4*)(OpA + pc);
        u32x4 aB = *(const u32x4*)(OpB + pc);
        unsigned hiw[4];
        #pragma unroll
        for (int q = 0; q < 4; ++q) {
            u16 ua0 = (u16)(aA[q] & 0xffffu), ua1 = (u16)(aA[q] >> 16);
            u16 ub0 = (u16)(aB[q] & 0xffffu), ub1 = (u16)(aB[q] >> 16);
            float v0 = (fb16(ua0) * waH + fb16(ub0) * wbH) * invH;
            float v1 = (fb16(ua1) * waH + fb16(ub1) * wbH) * invH;
            hiw[q] = pack2(v0, v1);
        }
        union { bf16x8 v; u32x4 u; } H;
        H.u = { hiw[0], hiw[1], hiw[2], hiw[3] };
        acc = MFMA(H.v, wh, acc);
        acc = MFMA(H.v, wl, acc);
    }
    #pragma unroll
    for (int r = 0; r < 16; ++r) {
        int n = (n5 << 5) + (r & 3) + 8 * (r >> 2) + 4 * hf;
        size_t off = ((size_t)(b * 2048 + n) * 256 + o0 + l31) * 3 + c;
        out[off] = acc[r];
    }
}

extern "C" void kernel_launch(void* const* d_in, const int* in_sizes, int n_in,
                              void* d_out, int out_size, void* d_ws, size_t ws_size,
                              hipStream_t stream) {
    const float* x     = (const float*)d_in[0];
    const float* w_qkv = (const float*)d_in[1];
    const float* w_out = (const float*)d_in[2];
    float* out = (float*)d_out;

    const size_t NB = (size_t)16 * 2048 * 192;       // 6.29M u16 per plane
    const size_t KVN = (size_t)16 * 64 * 18432;      // 18.87M u16
    const size_t XF = (size_t)3 * 2 * 64 * 16 * 512; // 3.15M u16 per x plane
    u16* Qhi = (u16*)d_ws;
    u16* Qlo = Qhi + NB;
    u16* KVf = Qlo + NB;
    u16* OpA = KVf + KVN;
    u16* OpB = OpA + NB;
    float2* MLp = (float2*)(OpB + NB);               // 512KB
    u16* xfh = (u16*)(MLp + 65536);
    u16* xfl = xfh + XF;
    u16* wfh = xfl + XF;                             // 393216 u16
    u16* wfl = wfh + (size_t)1536 * 256;
    u16* wofh = wfl + (size_t)1536 * 256;            // 131072 u16
    u16* wofl = wofh + (size_t)256 * 512;

    presplit<<<dim3(568), 256, 0, stream>>>(x, w_qkv, w_out, xfh, xfl, wfh, wfl, wofh, wofl);
    qkv_mfma<<<dim3(768), 256, 0, stream>>>(xfh, xfl, wfh, wfl, Qhi, Qlo, KVf);
    attn_mfma<<<dim3(512), 256, 0, stream>>>(Qhi, Qlo, KVf, OpA, OpB, MLp);
    out_mfma<<<dim3(768), 256, 0, stream>>>(OpA, OpB, MLp, wofh, wofl, out);
}

// Round 19
// 207.369 us; speedup vs baseline: 1.1304x; 1.0138x over previous
//
#include <hip/hip_runtime.h>
#include <hip/hip_bf16.h>

#define SCALE 0.07216878364870322f   // (3*64)^-0.5
#define LOG2E 1.4426950408889634f
// Q is pre-scaled by SCALE*LOG2E so attention logits are in log2 units.

typedef __bf16 bf16x8 __attribute__((ext_vector_type(8)));
typedef float f32x16 __attribute__((ext_vector_type(16)));
typedef float f32x4v __attribute__((ext_vector_type(4)));
typedef unsigned int u32x4 __attribute__((ext_vector_type(4)));
typedef unsigned int u32x2 __attribute__((ext_vector_type(2)));
typedef unsigned short u16;

#define MFMA(a, b, c) __builtin_amdgcn_mfma_f32_32x32x16_bf16(a, b, c, 0, 0, 0)
#define MFMA16(a, b, c) __builtin_amdgcn_mfma_f32_16x16x32_bf16(a, b, c, 0, 0, 0)

__device__ __forceinline__ u16 b16(float v) { return __builtin_bit_cast(u16, (__bf16)v); }
__device__ __forceinline__ float fb16(u16 u) {
    unsigned int t = (unsigned int)u << 16;
    return __builtin_bit_cast(float, t);
}
__device__ __forceinline__ unsigned int splitpack(float v) {
    u16 h = b16(v);
    float r = v - fb16(h);
    return (unsigned int)h | ((unsigned int)b16(r) << 16);
}
__device__ __forceinline__ unsigned int pack2(float a, float b) {
    return (unsigned int)b16(a) | ((unsigned int)b16(b) << 16);
}
__device__ __forceinline__ void gload16(const void* g, void* l) {
    __builtin_amdgcn_global_load_lds((const __attribute__((address_space(1))) void*)g,
                                     (__attribute__((address_space(3))) void*)l, 16, 0, 0);
}

// ---------------- K0: presplit x + weights into FRAG-MAJOR bf16 hi/lo --------
__global__ __launch_bounds__(256) void presplit(const float* __restrict__ x,
                                                const float* __restrict__ wq,
                                                const float* __restrict__ wo,
                                                u16* __restrict__ xfh, u16* __restrict__ xfl,
                                                u16* __restrict__ wfh, u16* __restrict__ wfl,
                                                u16* __restrict__ wofh, u16* __restrict__ wofl) {
    const int bid = blockIdx.x;
    const int tid = threadIdx.x;
    if (bid < 512) {                       // x: 64 nt x 2 b x 4 k0g
        __shared__ float LT[32 * 49];
        const int nt = bid & 63, b = (bid >> 6) & 1, k0g = bid >> 7;
        const int n0 = nt * 32;
        const int lane = tid & 63;
        const int c = tid >> 6;            // 0..3 (c==3 idle in phase 2)
        for (int k0 = k0g * 4; k0 < k0g * 4 + 4; ++k0) {
            __syncthreads();
            #pragma unroll
            for (int s = 0; s < 2; ++s) {
                int v = tid + s * 256;
                if (v < 384) {
                    int row = v / 12, col4 = v % 12;
                    f32x4v t = *(const f32x4v*)(x + ((size_t)(b * 2048 + n0 + row)) * 768
                                                + k0 * 48 + col4 * 4);
                    *(f32x4v*)&LT[row * 49 + col4 * 4] = t;
                }
            }
            __syncthreads();
            if (c < 3) {
                const int nl = lane & 31, kh = lane >> 5;
                const float* src = &LT[nl * 49 + kh * 24 + c];
                bf16x8 hv, lv;
                #pragma unroll
                for (int e = 0; e < 8; ++e) {
                    float v = src[e * 3];
                    __bf16 hi = (__bf16)v;
                    hv[e] = hi;
                    lv[e] = (__bf16)(v - (float)hi);
                }
                size_t off = ((((size_t)(c * 2 + b) * 64 + nt) * 16 + k0) * 512) + lane * 8;
                *(bf16x8*)(xfh + off) = hv;
                *(bf16x8*)(xfl + off) = lv;
            }
        }
    } else if (bid < 560) {                // w_qkv: 48 ot32 tiles
        const int ot32 = bid - 512;
        const int lane = tid & 63;
        const int kc0 = tid >> 6;
        const int o = ot32 * 32 + (lane & 31);
        const int kh = lane >> 5;
        #pragma unroll
        for (int s = 0; s < 4; ++s) {
            const int kc = kc0 * 4 + s;
            const float* src = wq + (size_t)o * 256 + kc * 16 + kh * 8;
            bf16x8 hv, lv;
            #pragma unroll
            for (int e = 0; e < 8; ++e) {
                float v = src[e];
                __bf16 hi = (__bf16)v;
                hv[e] = hi;
                lv[e] = (__bf16)(v - (float)hi);
            }
            size_t off = ((size_t)(ot32 * 16 + kc) * 512) + lane * 8;
            *(bf16x8*)(wfh + off) = hv;
            *(bf16x8*)(wfl + off) = lv;
        }
    } else {                               // w_out: 8 ot32 tiles
        const int ot32 = bid - 560;
        const int lane = tid & 63;
        const int ks0 = tid >> 6;
        const int o = ot32 * 32 + (lane & 31);
        const int kh = lane >> 5;
        #pragma unroll
        for (int s = 0; s < 8; ++s) {
            const int ks = ks0 * 8 + s;
            const float* src = wo + (size_t)o * 512 + ks * 16 + kh * 8;
            bf16x8 hv, lv;
            #pragma unroll
            for (int e = 0; e < 8; ++e) {
                float v = src[e];
                __bf16 hi = (__bf16)v;
                hv[e] = hi;
                lv[e] = (__bf16)(v - (float)hi);
            }
            size_t off = ((size_t)(ot32 * 32 + ks) * 512) + lane * 8;
            *(bf16x8*)(wofh + off) = hv;
            *(bf16x8*)(wofl + off) = lv;
        }
    }
}

// ---------------- K1: QKV projection, ALL operands frag-major: pure MFMA -----
__global__ __launch_bounds__(256) void qkv_mfma(const u16* __restrict__ xfh,
                                                const u16* __restrict__ xfl,
                                                const u16* __restrict__ wfh,
                                                const u16* __restrict__ wfl,
                                                u16* __restrict__ Qhi, u16* __restrict__ Qlo,
                                                u16* __restrict__ KVf) {
    __shared__ unsigned int ldsr[2][32][196];
    const int tid = threadIdx.x;
    const int lane = tid & 63, w = tid >> 6, hf = lane >> 5, l31 = lane & 31;
    const int lq = lane & 15, gq = lane >> 4;
    const int id = blockIdx.x;           // 0..767
    const int xcd = id & 7;
    const int jj = id >> 3;              // 0..95
    const int nb = xcd * 4 + jj / 24;    // 0..31
    const int ot = jj % 24;              // 0..23
    const int o0 = ot * 64;
    const int b = nb >> 4;
    const int n0 = (nb & 15) * 128;
    const int nw0 = n0 + w * 32;
    const int part = o0 >> 9;
    const int h = (o0 >> 6) & 7;
    const int bh = b * 8 + h;
    const int nt = (nb & 15) * 4 + w;

    const size_t xtb = (((size_t)b * 64 + nt) * 16) * 512 + lane * 8;
    const size_t cstride = (size_t)2 * 64 * 16 * 512;
    const size_t wtb0 = ((size_t)(o0 >> 5) * 16) * 512 + lane * 8;
    const size_t wtb1 = wtb0 + (size_t)16 * 512;

    f32x16 acc[3][2] = {};
    #pragma unroll 2
    for (int k0 = 0; k0 < 16; ++k0) {
        bf16x8 xh[3], xl[3], wh[2], wl[2];
        #pragma unroll
        for (int c = 0; c < 3; ++c) {
            xh[c] = *(const bf16x8*)(xfh + xtb + c * cstride + k0 * 512);
            xl[c] = *(const bf16x8*)(xfl + xtb + c * cstride + k0 * 512);
        }
        wh[0] = *(const bf16x8*)(wfh + wtb0 + k0 * 512);
        wl[0] = *(const bf16x8*)(wfl + wtb0 + k0 * 512);
        wh[1] = *(const bf16x8*)(wfh + wtb1 + k0 * 512);
        wl[1] = *(const bf16x8*)(wfl + wtb1 + k0 * 512);
        #pragma unroll
        for (int c = 0; c < 3; ++c)
            #pragma unroll
            for (int ot2 = 0; ot2 < 2; ++ot2) {
                acc[c][ot2] = MFMA(xh[c], wh[ot2], acc[c][ot2]);
                acc[c][ot2] = MFMA(xl[c], wh[ot2], acc[c][ot2]);
                acc[c][ot2] = MFMA(xh[c], wl[ot2], acc[c][ot2]);
            }
    }

    #pragma unroll
    for (int round = 0; round < 2; ++round) {
        __syncthreads();
        if ((w >> 1) == round) {
            unsigned int (*L)[196] = ldsr[w & 1];
            #pragma unroll
            for (int c = 0; c < 3; ++c)
                #pragma unroll
                for (int ot2 = 0; ot2 < 2; ++ot2)
                    #pragma unroll
                    for (int r = 0; r < 16; ++r) {
                        float v = acc[c][ot2][r];
                        if (part == 0) v *= (SCALE * LOG2E);
                        int nn = (r & 3) + 8 * (r >> 2) + 4 * hf;
                        int dcol = 3 * (ot2 * 32 + l31) + c;
                        L[nn][dcol] = (part == 2) ? (unsigned int)b16(v) : splitpack(v);
                    }
            if (part < 2) {
                #pragma unroll
                for (int is = 0; is < 2; ++is)
                    #pragma unroll
                    for (int kc = 0; kc < 6; ++kc) {
                        const unsigned int* p = &L[is * 16 + lq][kc * 32 + gq * 8];
                        u32x4 a = *(const u32x4*)p;
                        u32x4 bq = *(const u32x4*)(p + 4);
                        u32x4 hi = { (a[0] & 0xffffu) | (a[1] << 16), (a[2] & 0xffffu) | (a[3] << 16),
                                     (bq[0] & 0xffffu) | (bq[1] << 16), (bq[2] & 0xffffu) | (bq[3] << 16) };
                        u32x4 lo = { (a[0] >> 16) | (a[1] & 0xffff0000u), (a[2] >> 16) | (a[3] & 0xffff0000u),
                                     (bq[0] >> 16) | (bq[1] & 0xffff0000u), (bq[2] >> 16) | (bq[3] & 0xffff0000u) };
                        if (part == 0) {
                            size_t off = ((size_t)(bh * 128 + (nw0 >> 4) + is) * 6 + kc) * 512 + lane * 8;
                            *(u32x4*)(Qhi + off) = hi;
                            *(u32x4*)(Qlo + off) = lo;
                        } else {
                            size_t off = (size_t)(bh * 64 + (nw0 >> 5)) * 18432 + (is * 6 + kc) * 512 + lane * 8;
                            *(u32x4*)(KVf + off) = hi;
                            *(u32x4*)(KVf + off + 6144) = lo;
                        }
                    }
            } else {
                u16* vp = KVf + (size_t)(bh * 64 + (nw0 >> 5)) * 18432 + 12288 + lane * 8;
                #pragma unroll
                for (int d = 0; d < 12; ++d) {
                    unsigned int t[8];
                    #pragma unroll
                    for (int e = 0; e < 8; ++e)
                        t[e] = L[gq * 8 + e][d * 16 + lq];
                    u32x4 pk = { (t[0] & 0xffffu) | (t[1] << 16), (t[2] & 0xffffu) | (t[3] << 16),
                                 (t[4] & 0xffffu) | (t[5] << 16), (t[6] & 0xffffu) | (t[7] << 16) };
                    *(u32x4*)(vp + d * 512) = pk;
                }
            }
        }
    }
}

// ---------------- K2: MFMA flash attention (R14 + deferred l-reduction) ------
// grid 512 (XCD-swizzled), block 256, launch_bounds(256,2) -> 2 waves/SIMD.
// l kept as per-lane partial; cross-lane reduced ONCE in the epilogue
// (removes 4 bpermutes + one serial shuffle chain per t from the hot loop).
__global__ __launch_bounds__(256, 2) void attn_mfma(
    const u16* __restrict__ Qhi, const u16* __restrict__ Qlo,
    const u16* __restrict__ KVf, u16* __restrict__ OpA, u16* __restrict__ OpB,
    float2* __restrict__ MLp) {
    __shared__ __align__(16) u16 lds[2][18432];  // per buf: Khi[6144]|Klo[6144]|V[6144]
    const int tid = threadIdx.x;
    const int lane = tid & 63;
    const int wl = tid >> 6;
    const int g = lane >> 4;
    const int i = lane & 15;
    const int id = blockIdx.x;                     // 0..511
    const int rem = id >> 3;
    const int grp = ((rem >> 4) << 3) | (id & 7);  // 0..31: (bh,half)
    const int itile = rem & 15;
    const int bh = grp >> 1;
    const int half = grp & 1;

    bf16x8 qh[2][6], ql[2][6];
    #pragma unroll
    for (int is = 0; is < 2; ++is) {
        size_t qb = (size_t)(bh * 128 + itile * 8 + wl * 2 + is) * 3072 + (size_t)lane * 8;
        #pragma unroll
        for (int kc = 0; kc < 6; ++kc) {
            qh[is][kc] = *(const bf16x8*)(Qhi + qb + kc * 512);
            ql[is][kc] = *(const bf16x8*)(Qlo + qb + kc * 512);
        }
    }

    const char* gKV = (const char*)KVf + (size_t)bh * 2359296;
    auto stage = [&](int buf, int jtAbs) {
        const char* src = gKV + (size_t)jtAbs * 36864;
        char* dst = (char*)&lds[buf][0];
        #pragma unroll
        for (int s = 0; s < 9; ++s) {
            const int c16 = (tid + s * 256) * 16;
            gload16(src + c16, dst + c16);
        }
    };

    const int jt0 = half * 32;
    stage(0, jt0);
    __syncthreads();
    int cur = 0;

    f32x4v o[2][12] = {};
    float m_run[2] = {-1e30f, -1e30f};
    float l_part[2] = {0.f, 0.f};   // per-lane partial; reduced in epilogue

    for (int t = 0; t < 32; ++t) {
        if (t + 1 < 32) stage(cur ^ 1, jt0 + t + 1);
        const u16* L = &lds[cur][0];

        f32x4v s4[2][2] = {};
        __builtin_amdgcn_s_setprio(1);
        #pragma unroll
        for (int kc = 0; kc < 6; ++kc) {
            bf16x8 kh0 = *(const bf16x8*)&L[(unsigned)(kc * 512) + lane * 8];
            bf16x8 kh1 = *(const bf16x8*)&L[(unsigned)((6 + kc) * 512) + lane * 8];
            bf16x8 kl0 = *(const bf16x8*)&L[6144u + (unsigned)(kc * 512) + lane * 8];
            bf16x8 kl1 = *(const bf16x8*)&L[6144u + (unsigned)((6 + kc) * 512) + lane * 8];
            s4[0][0] = MFMA16(kh0, qh[0][kc], s4[0][0]);
            s4[0][1] = MFMA16(kh1, qh[0][kc], s4[0][1]);
            s4[1][0] = MFMA16(kh0, qh[1][kc], s4[1][0]);
            s4[1][1] = MFMA16(kh1, qh[1][kc], s4[1][1]);
            s4[0][0] = MFMA16(kh0, ql[0][kc], s4[0][0]);
            s4[0][1] = MFMA16(kh1, ql[0][kc], s4[0][1]);
            s4[1][0] = MFMA16(kh0, ql[1][kc], s4[1][0]);
            s4[1][1] = MFMA16(kh1, ql[1][kc], s4[1][1]);
            s4[0][0] = MFMA16(kl0, qh[0][kc], s4[0][0]);
            s4[0][1] = MFMA16(kl1, qh[0][kc], s4[0][1]);
            s4[1][0] = MFMA16(kl0, qh[1][kc], s4[1][0]);
            s4[1][1] = MFMA16(kl1, qh[1][kc], s4[1][1]);
        }
        __builtin_amdgcn_s_setprio(0);

        bf16x8 pb[2];
        #pragma unroll
        for (int is = 0; is < 2; ++is) {
            float pm = -1e30f;
            #pragma unroll
            for (int js = 0; js < 2; ++js)
                #pragma unroll
                for (int r = 0; r < 4; ++r) pm = fmaxf(pm, s4[is][js][r]);
            pm = fmaxf(pm, __shfl_xor(pm, 16, 64));
            pm = fmaxf(pm, __shfl_xor(pm, 32, 64));
            if (!__all(pm <= m_run[is] + 8.0f)) {   // T13 defer-rescale
                float mnew = fmaxf(m_run[is], pm);
                float sc = exp2f(m_run[is] - mnew);
                l_part[is] *= sc;
                #pragma unroll
                for (int d = 0; d < 12; ++d) o[is][d] = o[is][d] * sc;
                m_run[is] = mnew;
            }
            float rs = 0.f;
            unsigned int w0[2], w1[2];
            #pragma unroll
            for (int js = 0; js < 2; ++js) {
                float p0 = exp2f(s4[is][js][0] - m_run[is]), p1 = exp2f(s4[is][js][1] - m_run[is]);
                float p2 = exp2f(s4[is][js][2] - m_run[is]), p3 = exp2f(s4[is][js][3] - m_run[is]);
                rs += (p0 + p1) + (p2 + p3);
                w0[js] = pack2(p0, p1);
                w1[js] = pack2(p2, p3);
            }
            l_part[is] += rs;               // no cross-lane reduce in the loop

            u32x4 F;
            const int slA = ((g & 1) << 5) + i;
            const int slB = slA + 16;
            const bool ghi = (g >> 1) != 0;
            { unsigned a0 = __shfl((int)w0[0], slA, 64), a1 = __shfl((int)w0[1], slA, 64); F[0] = ghi ? a1 : a0; }
            { unsigned a0 = __shfl((int)w1[0], slA, 64), a1 = __shfl((int)w1[1], slA, 64); F[1] = ghi ? a1 : a0; }
            { unsigned a0 = __shfl((int)w0[0], slB, 64), a1 = __shfl((int)w0[1], slB, 64); F[2] = ghi ? a1 : a0; }
            { unsigned a0 = __shfl((int)w1[0], slB, 64), a1 = __shfl((int)w1[1], slB, 64); F[3] = ghi ? a1 : a0; }
            pb[is] = __builtin_bit_cast(bf16x8, F);
        }

        __builtin_amdgcn_s_setprio(1);
        #pragma unroll
        for (int d = 0; d < 12; ++d) {
            bf16x8 vf = *(const bf16x8*)&L[12288u + (unsigned)(d * 512) + lane * 8];
            o[0][d] = MFMA16(vf, pb[0], o[0][d]);
            o[1][d] = MFMA16(vf, pb[1], o[1][d]);
        }
        __builtin_amdgcn_s_setprio(0);

        if (t + 1 < 32) {
            __syncthreads();
            cur ^= 1;
        }
    }

    // ---- final l reduction (once) ----
    float l_run[2];
    #pragma unroll
    for (int is = 0; is < 2; ++is) {
        float l = l_part[is];
        l += __shfl_xor(l, 16, 64);
        l += __shfl_xor(l, 32, 64);
        l_run[is] = l;
    }

    // ---- epilogue: LDS transpose (row-stride 196 u16) -> coalesced stores ----
    __syncthreads();
    u16* LS = &lds[0][0];
    #pragma unroll
    for (int is = 0; is < 2; ++is) {
        const int row = (wl * 2 + is) * 16 + i;
        #pragma unroll
        for (int d = 0; d < 12; ++d) {
            u32x2 pk = { pack2(o[is][d][0], o[is][d][1]), pack2(o[is][d][2], o[is][d][3]) };
            *(u32x2*)&LS[row * 196 + d * 16 + g * 4] = pk;
        }
        if (g == 0) {
            const int ig = itile * 128 + row;
            float2 ml; ml.x = m_run[is]; ml.y = l_run[is];
            MLp[(size_t)half * 32768 + bh * 2048 + ig] = ml;
        }
    }
    __syncthreads();
    const int b2 = bh >> 3, hh = bh & 7;
    u16* P = half ? OpB : OpA;
    #pragma unroll
    for (int v = 0; v < 12; ++v) {
        const int Lx = v * 256 + tid;
        const int ln   = Lx & 63;
        const int itql = (Lx >> 6) & 3;
        const int ksl  = (Lx >> 8) & 3;
        const int c    = Lx >> 10;
        const int i31 = ln & 31, b5 = ln >> 5;
        const int rowl = itql * 32 + i31;
        unsigned tv[8];
        #pragma unroll
        for (int e = 0; e < 8; ++e) {
            const int dd = ksl * 16 + b5 * 8 + e;
            tv[e] = LS[rowl * 196 + dd * 3 + c];
        }
        u32x4 pk = { tv[0] | (tv[1] << 16), tv[2] | (tv[3] << 16),
                     tv[4] | (tv[5] << 16), tv[6] | (tv[7] << 16) };
        size_t off = (((size_t)(b2 * 3 + c) * 32 + (hh * 4 + ksl)) * 64 + (itile * 4 + itql)) * 512
                     + (size_t)ln * 8;
        *(u32x4*)(P + off) = pk;
    }
}

// ---------------- K3: output projection + inline flash merge, c-split grid ---
__global__ __launch_bounds__(256) void out_mfma(const u16* __restrict__ OpA,
                                                const u16* __restrict__ OpB,
                                                const float2* __restrict__ MLp,
                                                const u16* __restrict__ wofh,
                                                const u16* __restrict__ wofl,
                                                float* __restrict__ out) {
    const int tid = threadIdx.x, lane = tid & 63, w = tid >> 6, hf = lane >> 5, l31 = lane & 31;
    const int id = blockIdx.x;
    const int c = id >> 8;          // 0..2
    const int r5 = id & 255;
    const int xo = r5 & 7;
    const int yy = (r5 >> 3) & 15;
    const int b = r5 >> 7;
    const int o0 = xo * 32;
    const int n5 = yy * 4 + w;
    const size_t wtb = ((size_t)xo * 32) * 512 + lane * 8;

    float wa[8], wb[8], inv[8];
    #pragma unroll
    for (int hh = 0; hh < 8; ++hh) {
        size_t mi = (size_t)(b * 8 + hh) * 2048 + n5 * 32 + l31;
        float2 A = MLp[mi];
        float2 Bm = MLp[32768 + mi];
        float mm = fmaxf(A.x, Bm.x);
        wa[hh] = exp2f(A.x - mm);
        wb[hh] = exp2f(Bm.x - mm);
        inv[hh] = 1.0f / (A.y * wa[hh] + Bm.y * wb[hh]);
    }

    f32x16 acc = {};
    #pragma unroll 2
    for (int ks = 0; ks < 32; ++ks) {
        const int hh = ks >> 2;
        const float waH = wa[hh], wbH = wb[hh], invH = inv[hh];
        bf16x8 wh = *(const bf16x8*)(wofh + wtb + ks * 512);
        bf16x8 wl = *(const bf16x8*)(wofl + wtb + ks * 512);
        size_t pc = (size_t)(b * 3 + c) * 1048576 + (size_t)ks * 32768 + (size_t)n5 * 512 + (size_t)lane * 8;
        u32x4 aA = *(const u32x4*)(OpA + pc);
        u32x4 aB = *(const u32x4*)(OpB + pc);
        unsigned hiw[4];
        #pragma unroll
        for (int q = 0; q < 4; ++q) {
            u16 ua0 = (u16)(aA[q] & 0xffffu), ua1 = (u16)(aA[q] >> 16);
            u16 ub0 = (u16)(aB[q] & 0xffffu), ub1 = (u16)(aB[q] >> 16);
            float v0 = (fb16(ua0) * waH + fb16(ub0) * wbH) * invH;
            float v1 = (fb16(ua1) * waH + fb16(ub1) * wbH) * invH;
            hiw[q] = pack2(v0, v1);
        }
        union { bf16x8 v; u32x4 u; } H;
        H.u = { hiw[0], hiw[1], hiw[2], hiw[3] };
        acc = MFMA(H.v, wh, acc);
        acc = MFMA(H.v, wl, acc);
    }
    #pragma unroll
    for (int r = 0; r < 16; ++r) {
        int n = (n5 << 5) + (r & 3) + 8 * (r >> 2) + 4 * hf;
        size_t off = ((size_t)(b * 2048 + n) * 256 + o0 + l31) * 3 + c;
        out[off] = acc[r];
    }
}

extern "C" void kernel_launch(void* const* d_in, const int* in_sizes, int n_in,
                              void* d_out, int out_size, void* d_ws, size_t ws_size,
                              hipStream_t stream) {
    const float* x     = (const float*)d_in[0];
    const float* w_qkv = (const float*)d_in[1];
    const float* w_out = (const float*)d_in[2];
    float* out = (float*)d_out;

    const size_t NB = (size_t)16 * 2048 * 192;       // 6.29M u16 per plane
    const size_t KVN = (size_t)16 * 64 * 18432;      // 18.87M u16
    const size_t XF = (size_t)3 * 2 * 64 * 16 * 512; // 3.15M u16 per x plane
    u16* Qhi = (u16*)d_ws;
    u16* Qlo = Qhi + NB;
    u16* KVf = Qlo + NB;
    u16* OpA = KVf + KVN;
    u16* OpB = OpA + NB;
    float2* MLp = (float2*)(OpB + NB);               // 512KB
    u16* xfh = (u16*)(MLp + 65536);
    u16* xfl = xfh + XF;
    u16* wfh = xfl + XF;                             // 393216 u16
    u16* wfl = wfh + (size_t)1536 * 256;
    u16* wofh = wfl + (size_t)1536 * 256;            // 131072 u16
    u16* wofl = wofh + (size_t)256 * 512;

    presplit<<<dim3(568), 256, 0, stream>>>(x, w_qkv, w_out, xfh, xfl, wfh, wfl, wofh, wofl);
    qkv_mfma<<<dim3(768), 256, 0, stream>>>(xfh, xfl, wfh, wfl, Qhi, Qlo, KVf);
    attn_mfma<<<dim3(512), 256, 0, stream>>>(Qhi, Qlo, KVf, OpA, OpB, MLp);
    out_mfma<<<dim3(768), 256, 0, stream>>>(OpA, OpB, MLp, wofh, wofl, out);
}

// Round 20
// 206.049 us; speedup vs baseline: 1.1376x; 1.0064x over previous
//
#include <hip/hip_runtime.h>
#include <hip/hip_bf16.h>

#define SCALE 0.07216878364870322f   // (3*64)^-0.5
#define LOG2E 1.4426950408889634f
// Q is pre-scaled by SCALE*LOG2E so attention logits are in log2 units.

typedef __bf16 bf16x8 __attribute__((ext_vector_type(8)));
typedef float f32x16 __attribute__((ext_vector_type(16)));
typedef float f32x4v __attribute__((ext_vector_type(4)));
typedef unsigned int u32x4 __attribute__((ext_vector_type(4)));
typedef unsigned int u32x2 __attribute__((ext_vector_type(2)));
typedef unsigned short u16;

#define MFMA(a, b, c) __builtin_amdgcn_mfma_f32_32x32x16_bf16(a, b, c, 0, 0, 0)
#define MFMA16(a, b, c) __builtin_amdgcn_mfma_f32_16x16x32_bf16(a, b, c, 0, 0, 0)

__device__ __forceinline__ u16 b16(float v) { return __builtin_bit_cast(u16, (__bf16)v); }
__device__ __forceinline__ float fb16(u16 u) {
    unsigned int t = (unsigned int)u << 16;
    return __builtin_bit_cast(float, t);
}
__device__ __forceinline__ unsigned int splitpack(float v) {
    u16 h = b16(v);
    float r = v - fb16(h);
    return (unsigned int)h | ((unsigned int)b16(r) << 16);
}
__device__ __forceinline__ unsigned int pack2(float a, float b) {
    return (unsigned int)b16(a) | ((unsigned int)b16(b) << 16);
}
__device__ __forceinline__ void gload16(const void* g, void* l) {
    __builtin_amdgcn_global_load_lds((const __attribute__((address_space(1))) void*)g,
                                     (__attribute__((address_space(3))) void*)l, 16, 0, 0);
}

// ---------------- K0: presplit x + weights into FRAG-MAJOR bf16 hi/lo --------
__global__ __launch_bounds__(256) void presplit(const float* __restrict__ x,
                                                const float* __restrict__ wq,
                                                const float* __restrict__ wo,
                                                u16* __restrict__ xfh, u16* __restrict__ xfl,
                                                u16* __restrict__ wfh, u16* __restrict__ wfl,
                                                u16* __restrict__ wofh, u16* __restrict__ wofl) {
    const int bid = blockIdx.x;
    const int tid = threadIdx.x;
    if (bid < 512) {                       // x: 64 nt x 2 b x 4 k0g
        __shared__ float LT[32 * 49];
        const int nt = bid & 63, b = (bid >> 6) & 1, k0g = bid >> 7;
        const int n0 = nt * 32;
        const int lane = tid & 63;
        const int c = tid >> 6;            // 0..3 (c==3 idle in phase 2)
        for (int k0 = k0g * 4; k0 < k0g * 4 + 4; ++k0) {
            __syncthreads();
            #pragma unroll
            for (int s = 0; s < 2; ++s) {
                int v = tid + s * 256;
                if (v < 384) {
                    int row = v / 12, col4 = v % 12;
                    f32x4v t = *(const f32x4v*)(x + ((size_t)(b * 2048 + n0 + row)) * 768
                                                + k0 * 48 + col4 * 4);
                    *(f32x4v*)&LT[row * 49 + col4 * 4] = t;
                }
            }
            __syncthreads();
            if (c < 3) {
                const int nl = lane & 31, kh = lane >> 5;
                const float* src = &LT[nl * 49 + kh * 24 + c];
                bf16x8 hv, lv;
                #pragma unroll
                for (int e = 0; e < 8; ++e) {
                    float v = src[e * 3];
                    __bf16 hi = (__bf16)v;
                    hv[e] = hi;
                    lv[e] = (__bf16)(v - (float)hi);
                }
                size_t off = ((((size_t)(c * 2 + b) * 64 + nt) * 16 + k0) * 512) + lane * 8;
                *(bf16x8*)(xfh + off) = hv;
                *(bf16x8*)(xfl + off) = lv;
            }
        }
    } else if (bid < 560) {                // w_qkv: 48 ot32 tiles
        const int ot32 = bid - 512;
        const int lane = tid & 63;
        const int kc0 = tid >> 6;
        const int o = ot32 * 32 + (lane & 31);
        const int kh = lane >> 5;
        #pragma unroll
        for (int s = 0; s < 4; ++s) {
            const int kc = kc0 * 4 + s;
            const float* src = wq + (size_t)o * 256 + kc * 16 + kh * 8;
            bf16x8 hv, lv;
            #pragma unroll
            for (int e = 0; e < 8; ++e) {
                float v = src[e];
                __bf16 hi = (__bf16)v;
                hv[e] = hi;
                lv[e] = (__bf16)(v - (float)hi);
            }
            size_t off = ((size_t)(ot32 * 16 + kc) * 512) + lane * 8;
            *(bf16x8*)(wfh + off) = hv;
            *(bf16x8*)(wfl + off) = lv;
        }
    } else {                               // w_out: 8 ot32 tiles
        const int ot32 = bid - 560;
        const int lane = tid & 63;
        const int ks0 = tid >> 6;
        const int o = ot32 * 32 + (lane & 31);
        const int kh = lane >> 5;
        #pragma unroll
        for (int s = 0; s < 8; ++s) {
            const int ks = ks0 * 8 + s;
            const float* src = wo + (size_t)o * 512 + ks * 16 + kh * 8;
            bf16x8 hv, lv;
            #pragma unroll
            for (int e = 0; e < 8; ++e) {
                float v = src[e];
                __bf16 hi = (__bf16)v;
                hv[e] = hi;
                lv[e] = (__bf16)(v - (float)hi);
            }
            size_t off = ((size_t)(ot32 * 32 + ks) * 512) + lane * 8;
            *(bf16x8*)(wofh + off) = hv;
            *(bf16x8*)(wofl + off) = lv;
        }
    }
}

// ---------------- K1: QKV projection, ALL operands frag-major: pure MFMA -----
__global__ __launch_bounds__(256) void qkv_mfma(const u16* __restrict__ xfh,
                                                const u16* __restrict__ xfl,
                                                const u16* __restrict__ wfh,
                                                const u16* __restrict__ wfl,
                                                u16* __restrict__ Qhi, u16* __restrict__ Qlo,
                                                u16* __restrict__ KVf) {
    __shared__ unsigned int ldsr[2][32][196];
    const int tid = threadIdx.x;
    const int lane = tid & 63, w = tid >> 6, hf = lane >> 5, l31 = lane & 31;
    const int lq = lane & 15, gq = lane >> 4;
    const int id = blockIdx.x;           // 0..767
    const int xcd = id & 7;
    const int jj = id >> 3;              // 0..95
    const int nb = xcd * 4 + jj / 24;    // 0..31
    const int ot = jj % 24;              // 0..23
    const int o0 = ot * 64;
    const int b = nb >> 4;
    const int n0 = (nb & 15) * 128;
    const int nw0 = n0 + w * 32;
    const int part = o0 >> 9;
    const int h = (o0 >> 6) & 7;
    const int bh = b * 8 + h;
    const int nt = (nb & 15) * 4 + w;

    const size_t xtb = (((size_t)b * 64 + nt) * 16) * 512 + lane * 8;
    const size_t cstride = (size_t)2 * 64 * 16 * 512;
    const size_t wtb0 = ((size_t)(o0 >> 5) * 16) * 512 + lane * 8;
    const size_t wtb1 = wtb0 + (size_t)16 * 512;

    f32x16 acc[3][2] = {};
    #pragma unroll 2
    for (int k0 = 0; k0 < 16; ++k0) {
        bf16x8 xh[3], xl[3], wh[2], wl[2];
        #pragma unroll
        for (int c = 0; c < 3; ++c) {
            xh[c] = *(const bf16x8*)(xfh + xtb + c * cstride + k0 * 512);
            xl[c] = *(const bf16x8*)(xfl + xtb + c * cstride + k0 * 512);
        }
        wh[0] = *(const bf16x8*)(wfh + wtb0 + k0 * 512);
        wl[0] = *(const bf16x8*)(wfl + wtb0 + k0 * 512);
        wh[1] = *(const bf16x8*)(wfh + wtb1 + k0 * 512);
        wl[1] = *(const bf16x8*)(wfl + wtb1 + k0 * 512);
        #pragma unroll
        for (int c = 0; c < 3; ++c)
            #pragma unroll
            for (int ot2 = 0; ot2 < 2; ++ot2) {
                acc[c][ot2] = MFMA(xh[c], wh[ot2], acc[c][ot2]);
                acc[c][ot2] = MFMA(xl[c], wh[ot2], acc[c][ot2]);
                acc[c][ot2] = MFMA(xh[c], wl[ot2], acc[c][ot2]);
            }
    }

    #pragma unroll
    for (int round = 0; round < 2; ++round) {
        __syncthreads();
        if ((w >> 1) == round) {
            unsigned int (*L)[196] = ldsr[w & 1];
            #pragma unroll
            for (int c = 0; c < 3; ++c)
                #pragma unroll
                for (int ot2 = 0; ot2 < 2; ++ot2)
                    #pragma unroll
                    for (int r = 0; r < 16; ++r) {
                        float v = acc[c][ot2][r];
                        if (part == 0) v *= (SCALE * LOG2E);
                        int nn = (r & 3) + 8 * (r >> 2) + 4 * hf;
                        int dcol = 3 * (ot2 * 32 + l31) + c;
                        L[nn][dcol] = (part == 2) ? (unsigned int)b16(v) : splitpack(v);
                    }
            if (part < 2) {
                #pragma unroll
                for (int is = 0; is < 2; ++is)
                    #pragma unroll
                    for (int kc = 0; kc < 6; ++kc) {
                        const unsigned int* p = &L[is * 16 + lq][kc * 32 + gq * 8];
                        u32x4 a = *(const u32x4*)p;
                        u32x4 bq = *(const u32x4*)(p + 4);
                        u32x4 hi = { (a[0] & 0xffffu) | (a[1] << 16), (a[2] & 0xffffu) | (a[3] << 16),
                                     (bq[0] & 0xffffu) | (bq[1] << 16), (bq[2] & 0xffffu) | (bq[3] << 16) };
                        u32x4 lo = { (a[0] >> 16) | (a[1] & 0xffff0000u), (a[2] >> 16) | (a[3] & 0xffff0000u),
                                     (bq[0] >> 16) | (bq[1] & 0xffff0000u), (bq[2] >> 16) | (bq[3] & 0xffff0000u) };
                        if (part == 0) {
                            size_t off = ((size_t)(bh * 128 + (nw0 >> 4) + is) * 6 + kc) * 512 + lane * 8;
                            *(u32x4*)(Qhi + off) = hi;
                            *(u32x4*)(Qlo + off) = lo;
                        } else {
                            size_t off = (size_t)(bh * 64 + (nw0 >> 5)) * 18432 + (is * 6 + kc) * 512 + lane * 8;
                            *(u32x4*)(KVf + off) = hi;
                            *(u32x4*)(KVf + off + 6144) = lo;
                        }
                    }
            } else {
                u16* vp = KVf + (size_t)(bh * 64 + (nw0 >> 5)) * 18432 + 12288 + lane * 8;
                #pragma unroll
                for (int d = 0; d < 12; ++d) {
                    unsigned int t[8];
                    #pragma unroll
                    for (int e = 0; e < 8; ++e)
                        t[e] = L[gq * 8 + e][d * 16 + lq];
                    u32x4 pk = { (t[0] & 0xffffu) | (t[1] << 16), (t[2] & 0xffffu) | (t[3] << 16),
                                 (t[4] & 0xffffu) | (t[5] << 16), (t[6] & 0xffffu) | (t[7] << 16) };
                    *(u32x4*)(vp + d * 512) = pk;
                }
            }
        }
    }
}

// ---------------- K2: MFMA flash attention (R19 + lazy max-reduce) -----------
// Cross-lane max shuffles moved INSIDE the rare rescale branch: the guard uses
// per-lane local maxima via __all() (wave ballot, no shuffles). THR widened to
// 14 (P <= 2^14 in bf16, l <= 3.4e7 in f32 -- safe).
__global__ __launch_bounds__(256, 2) void attn_mfma(
    const u16* __restrict__ Qhi, const u16* __restrict__ Qlo,
    const u16* __restrict__ KVf, u16* __restrict__ OpA, u16* __restrict__ OpB,
    float2* __restrict__ MLp) {
    __shared__ __align__(16) u16 lds[2][18432];  // per buf: Khi[6144]|Klo[6144]|V[6144]
    const int tid = threadIdx.x;
    const int lane = tid & 63;
    const int wl = tid >> 6;
    const int g = lane >> 4;
    const int i = lane & 15;
    const int id = blockIdx.x;                     // 0..511
    const int rem = id >> 3;
    const int grp = ((rem >> 4) << 3) | (id & 7);  // 0..31: (bh,half)
    const int itile = rem & 15;
    const int bh = grp >> 1;
    const int half = grp & 1;

    bf16x8 qh[2][6], ql[2][6];
    #pragma unroll
    for (int is = 0; is < 2; ++is) {
        size_t qb = (size_t)(bh * 128 + itile * 8 + wl * 2 + is) * 3072 + (size_t)lane * 8;
        #pragma unroll
        for (int kc = 0; kc < 6; ++kc) {
            qh[is][kc] = *(const bf16x8*)(Qhi + qb + kc * 512);
            ql[is][kc] = *(const bf16x8*)(Qlo + qb + kc * 512);
        }
    }

    const char* gKV = (const char*)KVf + (size_t)bh * 2359296;
    auto stage = [&](int buf, int jtAbs) {
        const char* src = gKV + (size_t)jtAbs * 36864;
        char* dst = (char*)&lds[buf][0];
        #pragma unroll
        for (int s = 0; s < 9; ++s) {
            const int c16 = (tid + s * 256) * 16;
            gload16(src + c16, dst + c16);
        }
    };

    const int jt0 = half * 32;
    stage(0, jt0);
    __syncthreads();
    int cur = 0;

    f32x4v o[2][12] = {};
    float m_run[2] = {-1e30f, -1e30f};
    float l_part[2] = {0.f, 0.f};   // per-lane partial; reduced in epilogue

    for (int t = 0; t < 32; ++t) {
        if (t + 1 < 32) stage(cur ^ 1, jt0 + t + 1);
        const u16* L = &lds[cur][0];

        f32x4v s4[2][2] = {};
        __builtin_amdgcn_s_setprio(1);
        #pragma unroll
        for (int kc = 0; kc < 6; ++kc) {
            bf16x8 kh0 = *(const bf16x8*)&L[(unsigned)(kc * 512) + lane * 8];
            bf16x8 kh1 = *(const bf16x8*)&L[(unsigned)((6 + kc) * 512) + lane * 8];
            bf16x8 kl0 = *(const bf16x8*)&L[6144u + (unsigned)(kc * 512) + lane * 8];
            bf16x8 kl1 = *(const bf16x8*)&L[6144u + (unsigned)((6 + kc) * 512) + lane * 8];
            s4[0][0] = MFMA16(kh0, qh[0][kc], s4[0][0]);
            s4[0][1] = MFMA16(kh1, qh[0][kc], s4[0][1]);
            s4[1][0] = MFMA16(kh0, qh[1][kc], s4[1][0]);
            s4[1][1] = MFMA16(kh1, qh[1][kc], s4[1][1]);
            s4[0][0] = MFMA16(kh0, ql[0][kc], s4[0][0]);
            s4[0][1] = MFMA16(kh1, ql[0][kc], s4[0][1]);
            s4[1][0] = MFMA16(kh0, ql[1][kc], s4[1][0]);
            s4[1][1] = MFMA16(kh1, ql[1][kc], s4[1][1]);
            s4[0][0] = MFMA16(kl0, qh[0][kc], s4[0][0]);
            s4[0][1] = MFMA16(kl1, qh[0][kc], s4[0][1]);
            s4[1][0] = MFMA16(kl0, qh[1][kc], s4[1][0]);
            s4[1][1] = MFMA16(kl1, qh[1][kc], s4[1][1]);
        }
        __builtin_amdgcn_s_setprio(0);

        bf16x8 pb[2];
        #pragma unroll
        for (int is = 0; is < 2; ++is) {
            // per-lane local max only; cross-lane reduce deferred into the branch
            float pm = -1e30f;
            #pragma unroll
            for (int js = 0; js < 2; ++js)
                #pragma unroll
                for (int r = 0; r < 4; ++r) pm = fmaxf(pm, s4[is][js][r]);
            if (!__all(pm <= m_run[is] + 14.0f)) {   // rare: true max grew
                pm = fmaxf(pm, __shfl_xor(pm, 16, 64));
                pm = fmaxf(pm, __shfl_xor(pm, 32, 64));
                float mnew = fmaxf(m_run[is], pm);
                float sc = exp2f(m_run[is] - mnew);
                l_part[is] *= sc;
                #pragma unroll
                for (int d = 0; d < 12; ++d) o[is][d] = o[is][d] * sc;
                m_run[is] = mnew;
            }
            float rs = 0.f;
            unsigned int w0[2], w1[2];
            #pragma unroll
            for (int js = 0; js < 2; ++js) {
                float p0 = exp2f(s4[is][js][0] - m_run[is]), p1 = exp2f(s4[is][js][1] - m_run[is]);
                float p2 = exp2f(s4[is][js][2] - m_run[is]), p3 = exp2f(s4[is][js][3] - m_run[is]);
                rs += (p0 + p1) + (p2 + p3);
                w0[js] = pack2(p0, p1);
                w1[js] = pack2(p2, p3);
            }
            l_part[is] += rs;               // no cross-lane reduce in the loop

            u32x4 F;
            const int slA = ((g & 1) << 5) + i;
            const int slB = slA + 16;
            const bool ghi = (g >> 1) != 0;
            { unsigned a0 = __shfl((int)w0[0], slA, 64), a1 = __shfl((int)w0[1], slA, 64); F[0] = ghi ? a1 : a0; }
            { unsigned a0 = __shfl((int)w1[0], slA, 64), a1 = __shfl((int)w1[1], slA, 64); F[1] = ghi ? a1 : a0; }
            { unsigned a0 = __shfl((int)w0[0], slB, 64), a1 = __shfl((int)w0[1], slB, 64); F[2] = ghi ? a1 : a0; }
            { unsigned a0 = __shfl((int)w1[0], slB, 64), a1 = __shfl((int)w1[1], slB, 64); F[3] = ghi ? a1 : a0; }
            pb[is] = __builtin_bit_cast(bf16x8, F);
        }

        __builtin_amdgcn_s_setprio(1);
        #pragma unroll
        for (int d = 0; d < 12; ++d) {
            bf16x8 vf = *(const bf16x8*)&L[12288u + (unsigned)(d * 512) + lane * 8];
            o[0][d] = MFMA16(vf, pb[0], o[0][d]);
            o[1][d] = MFMA16(vf, pb[1], o[1][d]);
        }
        __builtin_amdgcn_s_setprio(0);

        if (t + 1 < 32) {
            __syncthreads();
            cur ^= 1;
        }
    }

    // ---- final l reduction (once) ----
    float l_run[2];
    #pragma unroll
    for (int is = 0; is < 2; ++is) {
        float l = l_part[is];
        l += __shfl_xor(l, 16, 64);
        l += __shfl_xor(l, 32, 64);
        l_run[is] = l;
    }

    // ---- epilogue: LDS transpose (row-stride 196 u16) -> coalesced stores ----
    __syncthreads();
    u16* LS = &lds[0][0];
    #pragma unroll
    for (int is = 0; is < 2; ++is) {
        const int row = (wl * 2 + is) * 16 + i;
        #pragma unroll
        for (int d = 0; d < 12; ++d) {
            u32x2 pk = { pack2(o[is][d][0], o[is][d][1]), pack2(o[is][d][2], o[is][d][3]) };
            *(u32x2*)&LS[row * 196 + d * 16 + g * 4] = pk;
        }
        if (g == 0) {
            const int ig = itile * 128 + row;
            float2 ml; ml.x = m_run[is]; ml.y = l_run[is];
            MLp[(size_t)half * 32768 + bh * 2048 + ig] = ml;
        }
    }
    __syncthreads();
    const int b2 = bh >> 3, hh = bh & 7;
    u16* P = half ? OpB : OpA;
    #pragma unroll
    for (int v = 0; v < 12; ++v) {
        const int Lx = v * 256 + tid;
        const int ln   = Lx & 63;
        const int itql = (Lx >> 6) & 3;
        const int ksl  = (Lx >> 8) & 3;
        const int c    = Lx >> 10;
        const int i31 = ln & 31, b5 = ln >> 5;
        const int rowl = itql * 32 + i31;
        unsigned tv[8];
        #pragma unroll
        for (int e = 0; e < 8; ++e) {
            const int dd = ksl * 16 + b5 * 8 + e;
            tv[e] = LS[rowl * 196 + dd * 3 + c];
        }
        u32x4 pk = { tv[0] | (tv[1] << 16), tv[2] | (tv[3] << 16),
                     tv[4] | (tv[5] << 16), tv[6] | (tv[7] << 16) };
        size_t off = (((size_t)(b2 * 3 + c) * 32 + (hh * 4 + ksl)) * 64 + (itile * 4 + itql)) * 512
                     + (size_t)ln * 8;
        *(u32x4*)(P + off) = pk;
    }
}

// ---------------- K3: output projection + inline flash merge, c-split grid ---
__global__ __launch_bounds__(256) void out_mfma(const u16* __restrict__ OpA,
                                                const u16* __restrict__ OpB,
                                                const float2* __restrict__ MLp,
                                                const u16* __restrict__ wofh,
                                                const u16* __restrict__ wofl,
                                                float* __restrict__ out) {
    const int tid = threadIdx.x, lane = tid & 63, w = tid >> 6, hf = lane >> 5, l31 = lane & 31;
    const int id = blockIdx.x;
    const int c = id >> 8;          // 0..2
    const int r5 = id & 255;
    const int xo = r5 & 7;
    const int yy = (r5 >> 3) & 15;
    const int b = r5 >> 7;
    const int o0 = xo * 32;
    const int n5 = yy * 4 + w;
    const size_t wtb = ((size_t)xo * 32) * 512 + lane * 8;

    float wa[8], wb[8], inv[8];
    #pragma unroll
    for (int hh = 0; hh < 8; ++hh) {
        size_t mi = (size_t)(b * 8 + hh) * 2048 + n5 * 32 + l31;
        float2 A = MLp[mi];
        float2 Bm = MLp[32768 + mi];
        float mm = fmaxf(A.x, Bm.x);
        wa[hh] = exp2f(A.x - mm);
        wb[hh] = exp2f(Bm.x - mm);
        inv[hh] = 1.0f / (A.y * wa[hh] + Bm.y * wb[hh]);
    }

    f32x16 acc = {};
    #pragma unroll 2
    for (int ks = 0; ks < 32; ++ks) {
        const int hh = ks >> 2;
        const float waH = wa[hh], wbH = wb[hh], invH = inv[hh];
        bf16x8 wh = *(const bf16x8*)(wofh + wtb + ks * 512);
        bf16x8 wl = *(const bf16x8*)(wofl + wtb + ks * 512);
        size_t pc = (size_t)(b * 3 + c) * 1048576 + (size_t)ks * 32768 + (size_t)n5 * 512 + (size_t)lane * 8;
        u32x4 aA = *(const u32x4*)(OpA + pc);
        u32x4 aB = *(const u32x4*)(OpB + pc);
        unsigned hiw[4];
        #pragma unroll
        for (int q = 0; q < 4; ++q) {
            u16 ua0 = (u16)(aA[q] & 0xffffu), ua1 = (u16)(aA[q] >> 16);
            u16 ub0 = (u16)(aB[q] & 0xffffu), ub1 = (u16)(aB[q] >> 16);
            float v0 = (fb16(ua0) * waH + fb16(ub0) * wbH) * invH;
            float v1 = (fb16(ua1) * waH + fb16(ub1) * wbH) * invH;
            hiw[q] = pack2(v0, v1);
        }
        union { bf16x8 v; u32x4 u; } H;
        H.u = { hiw[0], hiw[1], hiw[2], hiw[3] };
        acc = MFMA(H.v, wh, acc);
        acc = MFMA(H.v, wl, acc);
    }
    #pragma unroll
    for (int r = 0; r < 16; ++r) {
        int n = (n5 << 5) + (r & 3) + 8 * (r >> 2) + 4 * hf;
        size_t off = ((size_t)(b * 2048 + n) * 256 + o0 + l31) * 3 + c;
        out[off] = acc[r];
    }
}

extern "C" void kernel_launch(void* const* d_in, const int* in_sizes, int n_in,
                              void* d_out, int out_size, void* d_ws, size_t ws_size,
                              hipStream_t stream) {
    const float* x     = (const float*)d_in[0];
    const float* w_qkv = (const float*)d_in[1];
    const float* w_out = (const float*)d_in[2];
    float* out = (float*)d_out;

    const size_t NB = (size_t)16 * 2048 * 192;       // 6.29M u16 per plane
    const size_t KVN = (size_t)16 * 64 * 18432;      // 18.87M u16
    const size_t XF = (size_t)3 * 2 * 64 * 16 * 512; // 3.15M u16 per x plane
    u16* Qhi = (u16*)d_ws;
    u16* Qlo = Qhi + NB;
    u16* KVf = Qlo + NB;
    u16* OpA = KVf + KVN;
    u16* OpB = OpA + NB;
    float2* MLp = (float2*)(OpB + NB);               // 512KB
    u16* xfh = (u16*)(MLp + 65536);
    u16* xfl = xfh + XF;
    u16* wfh = xfl + XF;                             // 393216 u16
    u16* wfl = wfh + (size_t)1536 * 256;
    u16* wofh = wfl + (size_t)1536 * 256;            // 131072 u16
    u16* wofl = wofh + (size_t)256 * 512;

    presplit<<<dim3(568), 256, 0, stream>>>(x, w_qkv, w_out, xfh, xfl, wfh, wfl, wofh, wofl);
    qkv_mfma<<<dim3(768), 256, 0, stream>>>(xfh, xfl, wfh, wfl, Qhi, Qlo, KVf);
    attn_mfma<<<dim3(512), 256, 0, stream>>>(Qhi, Qlo, KVf, OpA, OpB, MLp);
    out_mfma<<<dim3(768), 256, 0, stream>>>(OpA, OpB, MLp, wofh, wofl, out);
}